// Round 5
// baseline (1354.496 us; speedup 1.0000x reference)
//
#include <hip/hip_runtime.h>

// KEPCE_GAT r5: parallel scan (3 kernels) + two-phase bucketed CSR build
// (bucket-major binning pass, then L2-local exact scatter). Agg kernels
// unchanged from r4 (thread-per-(node,head), online softmax, fused epilogue).

__device__ __forceinline__ float lrelu(float v){ return v > 0.f ? v : 0.2f*v; }

#define BSH 7   // bucket shift: 128 dsts per bucket

// Fold edge MLP: Wc[66,2] = w_e1[66,32] @ w_e2[32,2]; bc[2] = b_e1@w_e2 + b_e2.
__global__ void k_wcomb(const float* __restrict__ we1, const float* __restrict__ be1,
                        const float* __restrict__ we2, const float* __restrict__ be2,
                        float* __restrict__ wc, float* __restrict__ bc){
  int t = threadIdx.x;
  if (t < 132){
    int i = t >> 1, k = t & 1;
    float acc = 0.f;
    for (int j = 0; j < 32; ++j) acc += we1[i*32+j]*we2[j*2+k];
    wc[t] = acc;
  } else if (t < 134){
    int k = t - 132;
    float acc = be2[k];
    for (int j = 0; j < 32; ++j) acc += be1[j]*we2[j*2+k];
    bc[k] = acc;
  }
}

// In-degree histogram, 4 edges/thread.
__global__ void k_hist(const int* __restrict__ dst, int* __restrict__ deg, int E){
  int t = blockIdx.x*blockDim.x + threadIdx.x;
  int base = t << 2;
  if (base + 4 <= E){
    int4 d = *(const int4*)(dst + base);
    atomicAdd(&deg[d.x], 1); atomicAdd(&deg[d.y], 1);
    atomicAdd(&deg[d.z], 1); atomicAdd(&deg[d.w], 1);
  } else {
    for (int k = base; k < E; ++k) atomicAdd(&deg[dst[k]], 1);
  }
}

// Parallel scan stage 1: per-256-block sums.
__global__ void k_scan1(const int* __restrict__ deg, int* __restrict__ bsum, int n){
  __shared__ int lds[256];
  int t = threadIdx.x, k = blockIdx.x*256 + t;
  lds[t] = (k < n) ? deg[k] : 0;
  __syncthreads();
  #pragma unroll
  for (int off = 1; off < 256; off <<= 1){
    int u = (t >= off) ? lds[t-off] : 0;
    __syncthreads();
    lds[t] += u;
    __syncthreads();
  }
  if (t == 255) bsum[blockIdx.x] = lds[255];
}

// Stage 2: exclusive scan of block sums (nb <= 1024). One block.
__global__ void k_scan2(const int* __restrict__ bsum, int* __restrict__ boffs, int nb){
  __shared__ int lds[1024];
  int t = threadIdx.x;
  int v = (t < nb) ? bsum[t] : 0;
  lds[t] = v;
  __syncthreads();
  #pragma unroll
  for (int off = 1; off < 1024; off <<= 1){
    int u = (t >= off) ? lds[t-off] : 0;
    __syncthreads();
    lds[t] += u;
    __syncthreads();
  }
  if (t < nb) boffs[t] = lds[t] - v;
}

// Stage 3: final exclusive scan; writes rowstart, per-dst wptr, per-bucket bwptr.
__global__ void k_scan3(const int* __restrict__ deg, const int* __restrict__ boffs,
                        int* __restrict__ rowstart, int* __restrict__ wptr,
                        int* __restrict__ bwptr, int n){
  __shared__ int lds[256];
  int t = threadIdx.x, k = blockIdx.x*256 + t;
  int v = (k < n) ? deg[k] : 0;
  lds[t] = v;
  __syncthreads();
  #pragma unroll
  for (int off = 1; off < 256; off <<= 1){
    int u = (t >= off) ? lds[t-off] : 0;
    __syncthreads();
    lds[t] += u;
    __syncthreads();
  }
  if (k < n){
    int excl = boffs[blockIdx.x] + lds[t] - v;
    rowstart[k] = excl;
    wptr[k] = excl;
    if ((k & ((1<<BSH)-1)) == 0) bwptr[k >> BSH] = excl;
    if (k == n-1) rowstart[n] = excl + v;
  }
}

// Pass B: scatter edges into BUCKET-major order (782 sequential write
// frontiers -> dense line fill). tmp[pos] = {src, w, c, dst}.
__global__ void k_binB(const int* __restrict__ ei, const float* __restrict__ ew,
                       const float* __restrict__ ce, int* __restrict__ bwptr,
                       int4* __restrict__ tmp, int E){
  int e = blockIdx.x*blockDim.x + threadIdx.x;
  if (e >= E) return;
  int s = ei[e], d = ei[E+e];
  int pos = atomicAdd(&bwptr[d >> BSH], 1);
  tmp[pos] = make_int4(s, __float_as_int(ew[e]), __float_as_int(ce[e]), d);
}

// Pass C: exact per-dst scatter. Reads are bucket-ordered, so writes land in
// a ~64KB L2-resident CSR window -> full line merge.
__global__ void k_binC(const int4* __restrict__ tmp, int* __restrict__ wptr,
                       int4* __restrict__ csr, int E){
  int e = blockIdx.x*blockDim.x + threadIdx.x;
  if (e >= E) return;
  int4 v = tmp[e];
  int pos = atomicAdd(&wptr[v.w], 1);
  csr[pos] = v;
}

// Fused init+pre layer1: h0 = relu(x@wi+bi) in regs; xl1/xr1 = h0@Wl/Wr + b.
__global__ void k_pre1(const float* __restrict__ x, const float* __restrict__ wi,
                       const float* __restrict__ bi, const float* __restrict__ wl,
                       const float* __restrict__ bl, const float* __restrict__ wr,
                       const float* __restrict__ br, float* __restrict__ xl,
                       float* __restrict__ xr, int n){
  int i = blockIdx.x*blockDim.x + threadIdx.x;
  if (i >= n) return;
  float xi[5];
  #pragma unroll
  for (int j = 0; j < 5; ++j) xi[j] = x[i*5+j];
  float h[8];
  #pragma unroll
  for (int o = 0; o < 8; ++o){
    float acc = bi[o];
    #pragma unroll
    for (int j = 0; j < 5; ++j) acc += xi[j]*wi[j*8+o];
    h[o] = fmaxf(acc, 0.f);
  }
  #pragma unroll
  for (int o = 0; o < 16; ++o){
    float a = bl[o], r = br[o];
    #pragma unroll
    for (int j = 0; j < 8; ++j){ a += h[j]*wl[j*16+o]; r += h[j]*wr[j*16+o]; }
    xl[(size_t)i*16+o] = a;
    xr[(size_t)i*16+o] = r;
  }
}

// xl = hin@Wl+bl, xr = hin@Wr+br (layer2: 16 -> 32).
__global__ void k_pre2(const float* __restrict__ hin,
                       const float* __restrict__ wl, const float* __restrict__ bl,
                       const float* __restrict__ wr, const float* __restrict__ br,
                       float* __restrict__ xl, float* __restrict__ xr, int n){
  int i = blockIdx.x*blockDim.x + threadIdx.x;
  if (i >= n) return;
  float h[16];
  #pragma unroll
  for (int j = 0; j < 16; ++j) h[j] = hin[(size_t)i*16+j];
  #pragma unroll
  for (int o = 0; o < 32; ++o){
    float a = bl[o], r = br[o];
    #pragma unroll
    for (int j = 0; j < 16; ++j){ a += h[j]*wl[j*32+o]; r += h[j]*wr[j*32+o]; }
    xl[(size_t)i*32+o] = a;
    xr[(size_t)i*32+o] = r;
  }
}

// Layer-1 aggregation: 4 threads/node (one per head), C=4. Online softmax,
// edge-attr mean in-loop, self-loop last. h1 = relu(num/den + bias).
__global__ void k_agg1(const int* __restrict__ rowstart, const int4* __restrict__ csr,
                       const float* __restrict__ xl, const float* __restrict__ xr,
                       const float* __restrict__ we, const float* __restrict__ att,
                       const float* __restrict__ bias, float* __restrict__ hout, int n){
  constexpr int C = 4, HC = 16;
  int t = blockIdx.x*blockDim.x + threadIdx.x;
  int i = t >> 2, head = t & 3;
  if (i >= n) return;
  float weA[C], weB[C], AT[C], BS[C];
  #pragma unroll
  for (int c = 0; c < C; ++c){
    int o = head*C + c;
    weA[c] = we[o]; weB[c] = we[HC+o]; AT[c] = att[o]; BS[c] = bias[o];
  }
  float XR[C];
  {
    float4 b = *(const float4*)(xr + (size_t)i*HC + head*C);
    XR[0]=b.x; XR[1]=b.y; XR[2]=b.z; XR[3]=b.w;
  }
  float m = -3.0e38f, den = 0.f, sw = 0.f, sc = 0.f;
  float num[C] = {0.f,0.f,0.f,0.f};
  int rs = rowstart[i], re = rowstart[i+1];
  int j = rs;
  for (; j + 2 <= re; j += 2){
    int4 pa = csr[j], pb = csr[j+1];
    float4 qa = *(const float4*)(xl + (size_t)pa.x*HC + head*C);
    float4 qb = *(const float4*)(xl + (size_t)pb.x*HC + head*C);
    float f0a = __int_as_float(pa.y), f1a = __int_as_float(pa.z);
    float f0b = __int_as_float(pb.y), f1b = __int_as_float(pb.z);
    sw += f0a + f0b; sc += f1a + f1b;
    float XA[C] = {qa.x,qa.y,qa.z,qa.w};
    float XB[C] = {qb.x,qb.y,qb.z,qb.w};
    float aa = 0.f, ab = 0.f;
    #pragma unroll
    for (int c = 0; c < C; ++c) aa += AT[c]*lrelu(XA[c] + XR[c] + f0a*weA[c] + f1a*weB[c]);
    #pragma unroll
    for (int c = 0; c < C; ++c) ab += AT[c]*lrelu(XB[c] + XR[c] + f0b*weA[c] + f1b*weB[c]);
    float nm = fmaxf(m, aa);
    float r = __expf(m - nm), ex = __expf(aa - nm);
    den = den*r + ex;
    #pragma unroll
    for (int c = 0; c < C; ++c) num[c] = num[c]*r + ex*XA[c];
    m = nm;
    nm = fmaxf(m, ab); r = __expf(m - nm); ex = __expf(ab - nm);
    den = den*r + ex;
    #pragma unroll
    for (int c = 0; c < C; ++c) num[c] = num[c]*r + ex*XB[c];
    m = nm;
  }
  if (j < re){
    int4 pa = csr[j];
    float4 qa = *(const float4*)(xl + (size_t)pa.x*HC + head*C);
    float f0a = __int_as_float(pa.y), f1a = __int_as_float(pa.z);
    sw += f0a; sc += f1a;
    float XA[C] = {qa.x,qa.y,qa.z,qa.w};
    float aa = 0.f;
    #pragma unroll
    for (int c = 0; c < C; ++c) aa += AT[c]*lrelu(XA[c] + XR[c] + f0a*weA[c] + f1a*weB[c]);
    float nm = fmaxf(m, aa);
    float r = __expf(m - nm), ex = __expf(aa - nm);
    den = den*r + ex;
    #pragma unroll
    for (int c = 0; c < C; ++c) num[c] = num[c]*r + ex*XA[c];
    m = nm;
  }
  float cf = fmaxf((float)(re - rs), 1.f);
  float la0 = sw/cf, la1 = sc/cf;
  float4 qs = *(const float4*)(xl + (size_t)i*HC + head*C);
  float XS[C] = {qs.x,qs.y,qs.z,qs.w};
  float as = 0.f;
  #pragma unroll
  for (int c = 0; c < C; ++c) as += AT[c]*lrelu(XS[c] + XR[c] + la0*weA[c] + la1*weB[c]);
  float nm = fmaxf(m, as);
  float r = __expf(m - nm), ex = __expf(as - nm);
  den = den*r + ex;
  #pragma unroll
  for (int c = 0; c < C; ++c) num[c] = num[c]*r + ex*XS[c];
  float inv = 1.f/den;
  #pragma unroll
  for (int c = 0; c < C; ++c)
    hout[(size_t)i*HC + head*C + c] = fmaxf(num[c]*inv + BS[c], 0.f);
}

// Layer-2 aggregation (C=8) with fc + folded edge-MLP epilogue fused via LDS.
__global__ void k_agg2f(const int* __restrict__ rowstart, const int4* __restrict__ csr,
                        const float* __restrict__ xl, const float* __restrict__ xr,
                        const float* __restrict__ we, const float* __restrict__ att,
                        const float* __restrict__ bias, const float* __restrict__ wfc,
                        const float* __restrict__ bfc, const float* __restrict__ wc,
                        float* __restrict__ asrc, float* __restrict__ bdst, int n){
  constexpr int C = 8, HC = 32;
  __shared__ float s_h[64*33];
  __shared__ float s_w[1024];
  __shared__ float s_wc[134];
  int lt = threadIdx.x;
  for (int k = lt; k < 1024; k += 256) s_w[k] = wfc[k];
  if (lt < 134) s_wc[lt] = wc[lt];
  int t = blockIdx.x*blockDim.x + lt;
  int i = t >> 2, head = t & 3;
  bool valid = i < n;
  int ic = valid ? i : 0;
  float weA[C], weB[C], AT[C], BS[C];
  #pragma unroll
  for (int c = 0; c < C; ++c){
    int o = head*C + c;
    weA[c] = we[o]; weB[c] = we[HC+o]; AT[c] = att[o]; BS[c] = bias[o];
  }
  float XR[C];
  {
    const float4* pr = (const float4*)(xr + (size_t)ic*HC + head*C);
    float4 b0 = pr[0], b1 = pr[1];
    XR[0]=b0.x; XR[1]=b0.y; XR[2]=b0.z; XR[3]=b0.w;
    XR[4]=b1.x; XR[5]=b1.y; XR[6]=b1.z; XR[7]=b1.w;
  }
  float m = -3.0e38f, den = 0.f, sw = 0.f, sc = 0.f;
  float num[C] = {0.f,0.f,0.f,0.f,0.f,0.f,0.f,0.f};
  int rs = 0, re = 0;
  if (valid){ rs = rowstart[i]; re = rowstart[i+1]; }
  int j = rs;
  for (; j + 2 <= re; j += 2){
    int4 pa = csr[j], pb = csr[j+1];
    const float4* qa = (const float4*)(xl + (size_t)pa.x*HC + head*C);
    const float4* qb = (const float4*)(xl + (size_t)pb.x*HC + head*C);
    float4 a0 = qa[0], a1 = qa[1], b0 = qb[0], b1 = qb[1];
    float f0a = __int_as_float(pa.y), f1a = __int_as_float(pa.z);
    float f0b = __int_as_float(pb.y), f1b = __int_as_float(pb.z);
    sw += f0a + f0b; sc += f1a + f1b;
    float XA[C] = {a0.x,a0.y,a0.z,a0.w,a1.x,a1.y,a1.z,a1.w};
    float XB[C] = {b0.x,b0.y,b0.z,b0.w,b1.x,b1.y,b1.z,b1.w};
    float aa = 0.f, ab = 0.f;
    #pragma unroll
    for (int c = 0; c < C; ++c) aa += AT[c]*lrelu(XA[c] + XR[c] + f0a*weA[c] + f1a*weB[c]);
    #pragma unroll
    for (int c = 0; c < C; ++c) ab += AT[c]*lrelu(XB[c] + XR[c] + f0b*weA[c] + f1b*weB[c]);
    float nm = fmaxf(m, aa);
    float r = __expf(m - nm), ex = __expf(aa - nm);
    den = den*r + ex;
    #pragma unroll
    for (int c = 0; c < C; ++c) num[c] = num[c]*r + ex*XA[c];
    m = nm;
    nm = fmaxf(m, ab); r = __expf(m - nm); ex = __expf(ab - nm);
    den = den*r + ex;
    #pragma unroll
    for (int c = 0; c < C; ++c) num[c] = num[c]*r + ex*XB[c];
    m = nm;
  }
  if (j < re){
    int4 pa = csr[j];
    const float4* qa = (const float4*)(xl + (size_t)pa.x*HC + head*C);
    float4 a0 = qa[0], a1 = qa[1];
    float f0a = __int_as_float(pa.y), f1a = __int_as_float(pa.z);
    sw += f0a; sc += f1a;
    float XA[C] = {a0.x,a0.y,a0.z,a0.w,a1.x,a1.y,a1.z,a1.w};
    float aa = 0.f;
    #pragma unroll
    for (int c = 0; c < C; ++c) aa += AT[c]*lrelu(XA[c] + XR[c] + f0a*weA[c] + f1a*weB[c]);
    float nm = fmaxf(m, aa);
    float r = __expf(m - nm), ex = __expf(aa - nm);
    den = den*r + ex;
    #pragma unroll
    for (int c = 0; c < C; ++c) num[c] = num[c]*r + ex*XA[c];
    m = nm;
  }
  float out8[C];
  if (valid){
    float cf = fmaxf((float)(re - rs), 1.f);
    float la0 = sw/cf, la1 = sc/cf;
    const float4* pl = (const float4*)(xl + (size_t)i*HC + head*C);
    float4 s0 = pl[0], s1 = pl[1];
    float XS[C] = {s0.x,s0.y,s0.z,s0.w,s1.x,s1.y,s1.z,s1.w};
    float as = 0.f;
    #pragma unroll
    for (int c = 0; c < C; ++c) as += AT[c]*lrelu(XS[c] + XR[c] + la0*weA[c] + la1*weB[c]);
    float nm = fmaxf(m, as);
    float r = __expf(m - nm), ex = __expf(as - nm);
    den = den*r + ex;
    #pragma unroll
    for (int c = 0; c < C; ++c) num[c] = num[c]*r + ex*XS[c];
    float inv = 1.f/den;
    #pragma unroll
    for (int c = 0; c < C; ++c) out8[c] = fmaxf(num[c]*inv + BS[c], 0.f);
  } else {
    #pragma unroll
    for (int c = 0; c < C; ++c) out8[c] = 0.f;
  }
  int ln = lt >> 2;
  #pragma unroll
  for (int c = 0; c < C; ++c) s_h[ln*33 + head*C + c] = out8[c];
  __syncthreads();
  float hl[32];
  #pragma unroll
  for (int j2 = 0; j2 < 32; ++j2) hl[j2] = s_h[ln*33 + j2];
  float pa0=0.f, pa1=0.f, pb0=0.f, pb1=0.f;
  #pragma unroll
  for (int oc = 0; oc < 8; ++oc){
    int o = head*8 + oc;
    float acc = bfc[o];
    #pragma unroll
    for (int j2 = 0; j2 < 32; ++j2) acc += hl[j2]*s_w[j2*32+o];
    float f = fmaxf(acc, 0.f);
    pa0 += f*s_wc[(2+o)*2];  pa1 += f*s_wc[(2+o)*2+1];
    pb0 += f*s_wc[(34+o)*2]; pb1 += f*s_wc[(34+o)*2+1];
  }
  pa0 += __shfl_xor(pa0,1); pa0 += __shfl_xor(pa0,2);
  pa1 += __shfl_xor(pa1,1); pa1 += __shfl_xor(pa1,2);
  pb0 += __shfl_xor(pb0,1); pb0 += __shfl_xor(pb0,2);
  pb1 += __shfl_xor(pb1,1); pb1 += __shfl_xor(pb1,2);
  if (valid){
    if (head == 0)      ((float2*)asrc)[i] = make_float2(pa0, pa1);
    else if (head == 1) ((float2*)bdst)[i] = make_float2(pb0, pb1);
  }
}

// out[e] = ef[e]@Wc[0:2] + asrc[src] + bdst[dst] + bc  (float2 store)
__global__ void k_edge_final(const int* __restrict__ ei, const float* __restrict__ ew,
                             const float* __restrict__ ce, const float* __restrict__ asrc,
                             const float* __restrict__ bdst, const float* __restrict__ wc,
                             const float* __restrict__ bc, float2* __restrict__ out, int E){
  int e = blockIdx.x*blockDim.x + threadIdx.x;
  if (e >= E) return;
  int s = ei[e], d = ei[E+e];
  float f0 = ew[e], f1 = ce[e];
  float2 a = ((const float2*)asrc)[s];
  float2 b = ((const float2*)bdst)[d];
  out[e] = make_float2(f0*wc[0] + f1*wc[2] + a.x + b.x + bc[0],
                       f0*wc[1] + f1*wc[3] + a.y + b.y + bc[1]);
}

extern "C" void kernel_launch(void* const* d_in, const int* in_sizes, int n_in,
                              void* d_out, int out_size, void* d_ws, size_t ws_size,
                              hipStream_t stream){
  const float* x     = (const float*)d_in[0];
  const int*   ei    = (const int*)  d_in[1];
  const float* ew    = (const float*)d_in[2];
  const float* ce    = (const float*)d_in[3];
  const float* w_init= (const float*)d_in[4];
  const float* b_init= (const float*)d_in[5];
  const float* w1l   = (const float*)d_in[6];
  const float* b1l   = (const float*)d_in[7];
  const float* w1r   = (const float*)d_in[8];
  const float* b1r   = (const float*)d_in[9];
  const float* w1e   = (const float*)d_in[10];
  const float* att1  = (const float*)d_in[11];
  const float* bias1 = (const float*)d_in[12];
  const float* w2l   = (const float*)d_in[13];
  const float* b2l   = (const float*)d_in[14];
  const float* w2r   = (const float*)d_in[15];
  const float* b2r   = (const float*)d_in[16];
  const float* w2e   = (const float*)d_in[17];
  const float* att2  = (const float*)d_in[18];
  const float* bias2 = (const float*)d_in[19];
  const float* w_fc  = (const float*)d_in[20];
  const float* b_fc  = (const float*)d_in[21];
  const float* w_e1  = (const float*)d_in[22];
  const float* b_e1  = (const float*)d_in[23];
  const float* w_e2  = (const float*)d_in[24];
  const float* b_e2  = (const float*)d_in[25];

  const int n = in_sizes[0]/5;     // 100000
  const int E = in_sizes[2];       // 3200000
  const int NB  = (n + (1<<BSH) - 1) >> BSH;   // buckets
  const int nb1 = (n + 255) >> 8;              // scan blocks (<=1024)

  // ---- workspace layout: 128B-aligned (32 x 4B units) ----
  int*   W32 = (int*)d_ws;
  float* Wf  = (float*)d_ws;
  size_t off = 0;
  auto nxt = [&off](size_t cnt){ size_t p = off; off += (cnt + 31) & ~(size_t)31; return p; };
  int*   deg      = W32 + nxt(n);
  int*   rowstart = W32 + nxt((size_t)n + 1);
  int*   wptr     = W32 + nxt(n);
  int*   bwptr    = W32 + nxt(NB);
  int*   bsum     = W32 + nxt(nb1);
  int*   boffs    = W32 + nxt(nb1);
  float* wc       = Wf  + nxt(160);
  float* bc       = wc + 132;
  int4*  csr      = (int4*)(W32 + nxt((size_t)4*E));
  // big region: tmp (4E ints) aliased with node scratch S (80na) — tmp dead
  // before pre1 writes xl1.
  size_t na = ((size_t)n + 31) & ~(size_t)31;
  size_t bigsz = (size_t)4*E > 80*na ? (size_t)4*E : 80*na;
  float* S    = Wf + nxt(bigsz);
  int4*  tmp  = (int4*)S;
  float* xl1  = S;              // 16n, dead after agg1
  float* xr1  = S + 16*na;      // 16n, dead after agg1
  float* h1   = S + 32*na;      // 16n, dead after pre2
  float* xl2  = S;              // 32n (over xl1/xr1)
  float* xr2  = S + 48*na;      // 32n
  float* asrc = S + 32*na;      // 2n  (over h1, dead)
  float* bdst = S + 34*na;      // 2n

  dim3 blk(256);
  dim3 ge((E + 255)/256), gn((n + 255)/256);
  dim3 ge4(((E + 3)/4 + 255)/256), gn4(((size_t)4*n + 255)/256);

  hipMemsetAsync(deg, 0, (size_t)n*sizeof(int), stream);
  k_wcomb<<<1,192,0,stream>>>(w_e1,b_e1,w_e2,b_e2,wc,bc);

  // ---- CSR build: hist -> 3-stage scan -> bucket binning -> exact scatter ----
  k_hist<<<ge4,blk,0,stream>>>(ei + E, deg, E);
  k_scan1<<<nb1,256,0,stream>>>(deg,bsum,n);
  k_scan2<<<1,1024,0,stream>>>(bsum,boffs,nb1);
  k_scan3<<<nb1,256,0,stream>>>(deg,boffs,rowstart,wptr,bwptr,n);
  k_binB<<<ge,blk,0,stream>>>(ei,ew,ce,bwptr,tmp,E);
  k_binC<<<ge,blk,0,stream>>>(tmp,wptr,csr,E);

  // ---- GATv2 layer 1 (in 8, C=4) ----
  k_pre1<<<gn,blk,0,stream>>>(x,w_init,b_init,w1l,b1l,w1r,b1r,xl1,xr1,n);
  k_agg1<<<gn4,blk,0,stream>>>(rowstart,csr,xl1,xr1,w1e,att1,bias1,h1,n);

  // ---- GATv2 layer 2 (in 16, C=8) + fused fc/edge-MLP node terms ----
  k_pre2<<<gn,blk,0,stream>>>(h1,w2l,b2l,w2r,b2r,xl2,xr2,n);
  k_agg2f<<<gn4,blk,0,stream>>>(rowstart,csr,xl2,xr2,w2e,att2,bias2,w_fc,b_fc,wc,asrc,bdst,n);

  // ---- edge scores ----
  k_edge_final<<<ge,blk,0,stream>>>(ei,ew,ce,asrc,bdst,wc,bc,(float2*)d_out,E);
}

// Round 6
// 969.125 us; speedup vs baseline: 1.3976x; 1.3976x over previous
//
#include <hip/hip_runtime.h>

// KEPCE_GAT r6: r4 structure + parallel scan + two-step CSR build:
//   (a) scatter 4B edge-ids (perm fits in L2 -> write-merge),
//   (b) materialize int4 CSR by gather (streaming coalesced writes).
// Agg kernels: thread-per-(node,head), online softmax, fused fc epilogue.

__device__ __forceinline__ float lrelu(float v){ return v > 0.f ? v : 0.2f*v; }

// Fold edge MLP: Wc[66,2] = w_e1[66,32] @ w_e2[32,2]; bc[2] = b_e1@w_e2 + b_e2.
__global__ void k_wcomb(const float* __restrict__ we1, const float* __restrict__ be1,
                        const float* __restrict__ we2, const float* __restrict__ be2,
                        float* __restrict__ wc, float* __restrict__ bc){
  int t = threadIdx.x;
  if (t < 132){
    int i = t >> 1, k = t & 1;
    float acc = 0.f;
    for (int j = 0; j < 32; ++j) acc += we1[i*32+j]*we2[j*2+k];
    wc[t] = acc;
  } else if (t < 134){
    int k = t - 132;
    float acc = be2[k];
    for (int j = 0; j < 32; ++j) acc += be1[j]*we2[j*2+k];
    bc[k] = acc;
  }
}

// In-degree histogram, 4 edges/thread.
__global__ void k_hist(const int* __restrict__ dst, int* __restrict__ deg, int E){
  int t = blockIdx.x*blockDim.x + threadIdx.x;
  int base = t << 2;
  if (base + 4 <= E){
    int4 d = *(const int4*)(dst + base);
    atomicAdd(&deg[d.x], 1); atomicAdd(&deg[d.y], 1);
    atomicAdd(&deg[d.z], 1); atomicAdd(&deg[d.w], 1);
  } else {
    for (int k = base; k < E; ++k) atomicAdd(&deg[dst[k]], 1);
  }
}

// Parallel scan stage 1: per-256-block sums.
__global__ void k_scan1(const int* __restrict__ deg, int* __restrict__ bsum, int n){
  __shared__ int lds[256];
  int t = threadIdx.x, k = blockIdx.x*256 + t;
  lds[t] = (k < n) ? deg[k] : 0;
  __syncthreads();
  #pragma unroll
  for (int off = 1; off < 256; off <<= 1){
    int u = (t >= off) ? lds[t-off] : 0;
    __syncthreads();
    lds[t] += u;
    __syncthreads();
  }
  if (t == 255) bsum[blockIdx.x] = lds[255];
}

// Stage 2: exclusive scan of block sums (nb <= 1024). One block.
__global__ void k_scan2(const int* __restrict__ bsum, int* __restrict__ boffs, int nb){
  __shared__ int lds[1024];
  int t = threadIdx.x;
  int v = (t < nb) ? bsum[t] : 0;
  lds[t] = v;
  __syncthreads();
  #pragma unroll
  for (int off = 1; off < 1024; off <<= 1){
    int u = (t >= off) ? lds[t-off] : 0;
    __syncthreads();
    lds[t] += u;
    __syncthreads();
  }
  if (t < nb) boffs[t] = lds[t] - v;
}

// Stage 3: final exclusive scan -> rowstart, wptr.
__global__ void k_scan3(const int* __restrict__ deg, const int* __restrict__ boffs,
                        int* __restrict__ rowstart, int* __restrict__ wptr, int n){
  __shared__ int lds[256];
  int t = threadIdx.x, k = blockIdx.x*256 + t;
  int v = (k < n) ? deg[k] : 0;
  lds[t] = v;
  __syncthreads();
  #pragma unroll
  for (int off = 1; off < 256; off <<= 1){
    int u = (t >= off) ? lds[t-off] : 0;
    __syncthreads();
    lds[t] += u;
    __syncthreads();
  }
  if (k < n){
    int excl = boffs[blockIdx.x] + lds[t] - v;
    rowstart[k] = excl;
    wptr[k] = excl;
    if (k == n-1) rowstart[n] = excl + v;
  }
}

// Scatter edge IDs only (4B): perm array (12.8MB) fits in aggregate L2 ->
// same-line stores merge before writeback.
__global__ void k_scatter_eid(const int* __restrict__ dst, int* __restrict__ wptr,
                              int* __restrict__ perm, int E){
  int e = blockIdx.x*blockDim.x + threadIdx.x;
  if (e >= E) return;
  int pos = atomicAdd(&wptr[dst[e]], 1);
  perm[pos] = e;
}

// Materialize int4 CSR by gather: streaming read of perm, random (LLC-resident)
// gathers of src/ew/ce, fully-coalesced streaming int4 write.
__global__ void k_material(const int* __restrict__ perm, const int* __restrict__ ei,
                           const float* __restrict__ ew, const float* __restrict__ ce,
                           int4* __restrict__ csr, int E){
  int e = blockIdx.x*blockDim.x + threadIdx.x;
  if (e >= E) return;
  int p = perm[e];
  csr[e] = make_int4(ei[p], __float_as_int(ew[p]), __float_as_int(ce[p]), 0);
}

// Fused init+pre layer1: h0 = relu(x@wi+bi) in regs; xl1/xr1 = h0@Wl/Wr + b.
__global__ void k_pre1(const float* __restrict__ x, const float* __restrict__ wi,
                       const float* __restrict__ bi, const float* __restrict__ wl,
                       const float* __restrict__ bl, const float* __restrict__ wr,
                       const float* __restrict__ br, float* __restrict__ xl,
                       float* __restrict__ xr, int n){
  int i = blockIdx.x*blockDim.x + threadIdx.x;
  if (i >= n) return;
  float xi[5];
  #pragma unroll
  for (int j = 0; j < 5; ++j) xi[j] = x[i*5+j];
  float h[8];
  #pragma unroll
  for (int o = 0; o < 8; ++o){
    float acc = bi[o];
    #pragma unroll
    for (int j = 0; j < 5; ++j) acc += xi[j]*wi[j*8+o];
    h[o] = fmaxf(acc, 0.f);
  }
  #pragma unroll
  for (int o = 0; o < 16; ++o){
    float a = bl[o], r = br[o];
    #pragma unroll
    for (int j = 0; j < 8; ++j){ a += h[j]*wl[j*16+o]; r += h[j]*wr[j*16+o]; }
    xl[(size_t)i*16+o] = a;
    xr[(size_t)i*16+o] = r;
  }
}

// xl = hin@Wl+bl, xr = hin@Wr+br (layer2: 16 -> 32).
__global__ void k_pre2(const float* __restrict__ hin,
                       const float* __restrict__ wl, const float* __restrict__ bl,
                       const float* __restrict__ wr, const float* __restrict__ br,
                       float* __restrict__ xl, float* __restrict__ xr, int n){
  int i = blockIdx.x*blockDim.x + threadIdx.x;
  if (i >= n) return;
  float h[16];
  #pragma unroll
  for (int j = 0; j < 16; ++j) h[j] = hin[(size_t)i*16+j];
  #pragma unroll
  for (int o = 0; o < 32; ++o){
    float a = bl[o], r = br[o];
    #pragma unroll
    for (int j = 0; j < 16; ++j){ a += h[j]*wl[j*32+o]; r += h[j]*wr[j*32+o]; }
    xl[(size_t)i*32+o] = a;
    xr[(size_t)i*32+o] = r;
  }
}

// Layer-1 aggregation: 4 threads/node (one per head), C=4. Online softmax,
// edge-attr mean in-loop, self-loop last. h1 = relu(num/den + bias).
__global__ void k_agg1(const int* __restrict__ rowstart, const int4* __restrict__ csr,
                       const float* __restrict__ xl, const float* __restrict__ xr,
                       const float* __restrict__ we, const float* __restrict__ att,
                       const float* __restrict__ bias, float* __restrict__ hout, int n){
  constexpr int C = 4, HC = 16;
  int t = blockIdx.x*blockDim.x + threadIdx.x;
  int i = t >> 2, head = t & 3;
  if (i >= n) return;
  float weA[C], weB[C], AT[C], BS[C];
  #pragma unroll
  for (int c = 0; c < C; ++c){
    int o = head*C + c;
    weA[c] = we[o]; weB[c] = we[HC+o]; AT[c] = att[o]; BS[c] = bias[o];
  }
  float XR[C];
  {
    float4 b = *(const float4*)(xr + (size_t)i*HC + head*C);
    XR[0]=b.x; XR[1]=b.y; XR[2]=b.z; XR[3]=b.w;
  }
  float m = -3.0e38f, den = 0.f, sw = 0.f, sc = 0.f;
  float num[C] = {0.f,0.f,0.f,0.f};
  int rs = rowstart[i], re = rowstart[i+1];
  int j = rs;
  for (; j + 2 <= re; j += 2){
    int4 pa = csr[j], pb = csr[j+1];
    float4 qa = *(const float4*)(xl + (size_t)pa.x*HC + head*C);
    float4 qb = *(const float4*)(xl + (size_t)pb.x*HC + head*C);
    float f0a = __int_as_float(pa.y), f1a = __int_as_float(pa.z);
    float f0b = __int_as_float(pb.y), f1b = __int_as_float(pb.z);
    sw += f0a + f0b; sc += f1a + f1b;
    float XA[C] = {qa.x,qa.y,qa.z,qa.w};
    float XB[C] = {qb.x,qb.y,qb.z,qb.w};
    float aa = 0.f, ab = 0.f;
    #pragma unroll
    for (int c = 0; c < C; ++c) aa += AT[c]*lrelu(XA[c] + XR[c] + f0a*weA[c] + f1a*weB[c]);
    #pragma unroll
    for (int c = 0; c < C; ++c) ab += AT[c]*lrelu(XB[c] + XR[c] + f0b*weA[c] + f1b*weB[c]);
    float nm = fmaxf(m, aa);
    float r = __expf(m - nm), ex = __expf(aa - nm);
    den = den*r + ex;
    #pragma unroll
    for (int c = 0; c < C; ++c) num[c] = num[c]*r + ex*XA[c];
    m = nm;
    nm = fmaxf(m, ab); r = __expf(m - nm); ex = __expf(ab - nm);
    den = den*r + ex;
    #pragma unroll
    for (int c = 0; c < C; ++c) num[c] = num[c]*r + ex*XB[c];
    m = nm;
  }
  if (j < re){
    int4 pa = csr[j];
    float4 qa = *(const float4*)(xl + (size_t)pa.x*HC + head*C);
    float f0a = __int_as_float(pa.y), f1a = __int_as_float(pa.z);
    sw += f0a; sc += f1a;
    float XA[C] = {qa.x,qa.y,qa.z,qa.w};
    float aa = 0.f;
    #pragma unroll
    for (int c = 0; c < C; ++c) aa += AT[c]*lrelu(XA[c] + XR[c] + f0a*weA[c] + f1a*weB[c]);
    float nm = fmaxf(m, aa);
    float r = __expf(m - nm), ex = __expf(aa - nm);
    den = den*r + ex;
    #pragma unroll
    for (int c = 0; c < C; ++c) num[c] = num[c]*r + ex*XA[c];
    m = nm;
  }
  float cf = fmaxf((float)(re - rs), 1.f);
  float la0 = sw/cf, la1 = sc/cf;
  float4 qs = *(const float4*)(xl + (size_t)i*HC + head*C);
  float XS[C] = {qs.x,qs.y,qs.z,qs.w};
  float as = 0.f;
  #pragma unroll
  for (int c = 0; c < C; ++c) as += AT[c]*lrelu(XS[c] + XR[c] + la0*weA[c] + la1*weB[c]);
  float nm = fmaxf(m, as);
  float r = __expf(m - nm), ex = __expf(as - nm);
  den = den*r + ex;
  #pragma unroll
  for (int c = 0; c < C; ++c) num[c] = num[c]*r + ex*XS[c];
  float inv = 1.f/den;
  #pragma unroll
  for (int c = 0; c < C; ++c)
    hout[(size_t)i*HC + head*C + c] = fmaxf(num[c]*inv + BS[c], 0.f);
}

// Layer-2 aggregation (C=8) with fc + folded edge-MLP epilogue fused via LDS.
__global__ void k_agg2f(const int* __restrict__ rowstart, const int4* __restrict__ csr,
                        const float* __restrict__ xl, const float* __restrict__ xr,
                        const float* __restrict__ we, const float* __restrict__ att,
                        const float* __restrict__ bias, const float* __restrict__ wfc,
                        const float* __restrict__ bfc, const float* __restrict__ wc,
                        float* __restrict__ asrc, float* __restrict__ bdst, int n){
  constexpr int C = 8, HC = 32;
  __shared__ float s_h[64*33];
  __shared__ float s_w[1024];
  __shared__ float s_wc[134];
  int lt = threadIdx.x;
  for (int k = lt; k < 1024; k += 256) s_w[k] = wfc[k];
  if (lt < 134) s_wc[lt] = wc[lt];
  int t = blockIdx.x*blockDim.x + lt;
  int i = t >> 2, head = t & 3;
  bool valid = i < n;
  int ic = valid ? i : 0;
  float weA[C], weB[C], AT[C], BS[C];
  #pragma unroll
  for (int c = 0; c < C; ++c){
    int o = head*C + c;
    weA[c] = we[o]; weB[c] = we[HC+o]; AT[c] = att[o]; BS[c] = bias[o];
  }
  float XR[C];
  {
    const float4* pr = (const float4*)(xr + (size_t)ic*HC + head*C);
    float4 b0 = pr[0], b1 = pr[1];
    XR[0]=b0.x; XR[1]=b0.y; XR[2]=b0.z; XR[3]=b0.w;
    XR[4]=b1.x; XR[5]=b1.y; XR[6]=b1.z; XR[7]=b1.w;
  }
  float m = -3.0e38f, den = 0.f, sw = 0.f, sc = 0.f;
  float num[C] = {0.f,0.f,0.f,0.f,0.f,0.f,0.f,0.f};
  int rs = 0, re = 0;
  if (valid){ rs = rowstart[i]; re = rowstart[i+1]; }
  int j = rs;
  for (; j + 2 <= re; j += 2){
    int4 pa = csr[j], pb = csr[j+1];
    const float4* qa = (const float4*)(xl + (size_t)pa.x*HC + head*C);
    const float4* qb = (const float4*)(xl + (size_t)pb.x*HC + head*C);
    float4 a0 = qa[0], a1 = qa[1], b0 = qb[0], b1 = qb[1];
    float f0a = __int_as_float(pa.y), f1a = __int_as_float(pa.z);
    float f0b = __int_as_float(pb.y), f1b = __int_as_float(pb.z);
    sw += f0a + f0b; sc += f1a + f1b;
    float XA[C] = {a0.x,a0.y,a0.z,a0.w,a1.x,a1.y,a1.z,a1.w};
    float XB[C] = {b0.x,b0.y,b0.z,b0.w,b1.x,b1.y,b1.z,b1.w};
    float aa = 0.f, ab = 0.f;
    #pragma unroll
    for (int c = 0; c < C; ++c) aa += AT[c]*lrelu(XA[c] + XR[c] + f0a*weA[c] + f1a*weB[c]);
    #pragma unroll
    for (int c = 0; c < C; ++c) ab += AT[c]*lrelu(XB[c] + XR[c] + f0b*weA[c] + f1b*weB[c]);
    float nm = fmaxf(m, aa);
    float r = __expf(m - nm), ex = __expf(aa - nm);
    den = den*r + ex;
    #pragma unroll
    for (int c = 0; c < C; ++c) num[c] = num[c]*r + ex*XA[c];
    m = nm;
    nm = fmaxf(m, ab); r = __expf(m - nm); ex = __expf(ab - nm);
    den = den*r + ex;
    #pragma unroll
    for (int c = 0; c < C; ++c) num[c] = num[c]*r + ex*XB[c];
    m = nm;
  }
  if (j < re){
    int4 pa = csr[j];
    const float4* qa = (const float4*)(xl + (size_t)pa.x*HC + head*C);
    float4 a0 = qa[0], a1 = qa[1];
    float f0a = __int_as_float(pa.y), f1a = __int_as_float(pa.z);
    sw += f0a; sc += f1a;
    float XA[C] = {a0.x,a0.y,a0.z,a0.w,a1.x,a1.y,a1.z,a1.w};
    float aa = 0.f;
    #pragma unroll
    for (int c = 0; c < C; ++c) aa += AT[c]*lrelu(XA[c] + XR[c] + f0a*weA[c] + f1a*weB[c]);
    float nm = fmaxf(m, aa);
    float r = __expf(m - nm), ex = __expf(aa - nm);
    den = den*r + ex;
    #pragma unroll
    for (int c = 0; c < C; ++c) num[c] = num[c]*r + ex*XA[c];
    m = nm;
  }
  float out8[C];
  if (valid){
    float cf = fmaxf((float)(re - rs), 1.f);
    float la0 = sw/cf, la1 = sc/cf;
    const float4* pl = (const float4*)(xl + (size_t)i*HC + head*C);
    float4 s0 = pl[0], s1 = pl[1];
    float XS[C] = {s0.x,s0.y,s0.z,s0.w,s1.x,s1.y,s1.z,s1.w};
    float as = 0.f;
    #pragma unroll
    for (int c = 0; c < C; ++c) as += AT[c]*lrelu(XS[c] + XR[c] + la0*weA[c] + la1*weB[c]);
    float nm = fmaxf(m, as);
    float r = __expf(m - nm), ex = __expf(as - nm);
    den = den*r + ex;
    #pragma unroll
    for (int c = 0; c < C; ++c) num[c] = num[c]*r + ex*XS[c];
    float inv = 1.f/den;
    #pragma unroll
    for (int c = 0; c < C; ++c) out8[c] = fmaxf(num[c]*inv + BS[c], 0.f);
  } else {
    #pragma unroll
    for (int c = 0; c < C; ++c) out8[c] = 0.f;
  }
  int ln = lt >> 2;
  #pragma unroll
  for (int c = 0; c < C; ++c) s_h[ln*33 + head*C + c] = out8[c];
  __syncthreads();
  float hl[32];
  #pragma unroll
  for (int j2 = 0; j2 < 32; ++j2) hl[j2] = s_h[ln*33 + j2];
  float pa0=0.f, pa1=0.f, pb0=0.f, pb1=0.f;
  #pragma unroll
  for (int oc = 0; oc < 8; ++oc){
    int o = head*8 + oc;
    float acc = bfc[o];
    #pragma unroll
    for (int j2 = 0; j2 < 32; ++j2) acc += hl[j2]*s_w[j2*32+o];
    float f = fmaxf(acc, 0.f);
    pa0 += f*s_wc[(2+o)*2];  pa1 += f*s_wc[(2+o)*2+1];
    pb0 += f*s_wc[(34+o)*2]; pb1 += f*s_wc[(34+o)*2+1];
  }
  pa0 += __shfl_xor(pa0,1); pa0 += __shfl_xor(pa0,2);
  pa1 += __shfl_xor(pa1,1); pa1 += __shfl_xor(pa1,2);
  pb0 += __shfl_xor(pb0,1); pb0 += __shfl_xor(pb0,2);
  pb1 += __shfl_xor(pb1,1); pb1 += __shfl_xor(pb1,2);
  if (valid){
    if (head == 0)      ((float2*)asrc)[i] = make_float2(pa0, pa1);
    else if (head == 1) ((float2*)bdst)[i] = make_float2(pb0, pb1);
  }
}

// out[e] = ef[e]@Wc[0:2] + asrc[src] + bdst[dst] + bc  (float2 store)
__global__ void k_edge_final(const int* __restrict__ ei, const float* __restrict__ ew,
                             const float* __restrict__ ce, const float* __restrict__ asrc,
                             const float* __restrict__ bdst, const float* __restrict__ wc,
                             const float* __restrict__ bc, float2* __restrict__ out, int E){
  int e = blockIdx.x*blockDim.x + threadIdx.x;
  if (e >= E) return;
  int s = ei[e], d = ei[E+e];
  float f0 = ew[e], f1 = ce[e];
  float2 a = ((const float2*)asrc)[s];
  float2 b = ((const float2*)bdst)[d];
  out[e] = make_float2(f0*wc[0] + f1*wc[2] + a.x + b.x + bc[0],
                       f0*wc[1] + f1*wc[3] + a.y + b.y + bc[1]);
}

extern "C" void kernel_launch(void* const* d_in, const int* in_sizes, int n_in,
                              void* d_out, int out_size, void* d_ws, size_t ws_size,
                              hipStream_t stream){
  const float* x     = (const float*)d_in[0];
  const int*   ei    = (const int*)  d_in[1];
  const float* ew    = (const float*)d_in[2];
  const float* ce    = (const float*)d_in[3];
  const float* w_init= (const float*)d_in[4];
  const float* b_init= (const float*)d_in[5];
  const float* w1l   = (const float*)d_in[6];
  const float* b1l   = (const float*)d_in[7];
  const float* w1r   = (const float*)d_in[8];
  const float* b1r   = (const float*)d_in[9];
  const float* w1e   = (const float*)d_in[10];
  const float* att1  = (const float*)d_in[11];
  const float* bias1 = (const float*)d_in[12];
  const float* w2l   = (const float*)d_in[13];
  const float* b2l   = (const float*)d_in[14];
  const float* w2r   = (const float*)d_in[15];
  const float* b2r   = (const float*)d_in[16];
  const float* w2e   = (const float*)d_in[17];
  const float* att2  = (const float*)d_in[18];
  const float* bias2 = (const float*)d_in[19];
  const float* w_fc  = (const float*)d_in[20];
  const float* b_fc  = (const float*)d_in[21];
  const float* w_e1  = (const float*)d_in[22];
  const float* b_e1  = (const float*)d_in[23];
  const float* w_e2  = (const float*)d_in[24];
  const float* b_e2  = (const float*)d_in[25];

  const int n = in_sizes[0]/5;     // 100000
  const int E = in_sizes[2];       // 3200000
  const int nb1 = (n + 255) >> 8;  // scan blocks (<=1024)

  // ---- workspace layout: 128B-aligned (32 x 4B units) ----
  int*   W32 = (int*)d_ws;
  float* Wf  = (float*)d_ws;
  size_t off = 0;
  auto nxt = [&off](size_t cnt){ size_t p = off; off += (cnt + 31) & ~(size_t)31; return p; };
  int*   deg      = W32 + nxt(n);
  int*   rowstart = W32 + nxt((size_t)n + 1);
  int*   wptr     = W32 + nxt(n);
  int*   bsum     = W32 + nxt(nb1);
  int*   boffs    = W32 + nxt(nb1);
  float* wc       = Wf  + nxt(160);
  float* bc       = wc + 132;
  int4*  csr      = (int4*)(W32 + nxt((size_t)4*E));
  // big region: perm (E ints) aliased with node scratch S (80na floats) —
  // perm dead after k_material, before pre1 writes xl1.
  size_t na = ((size_t)n + 31) & ~(size_t)31;
  size_t bigsz = (size_t)E > 80*na ? (size_t)E : 80*na;
  float* S    = Wf + nxt(bigsz);
  int*   perm = (int*)S;
  float* xl1  = S;              // 16n, dead after agg1
  float* xr1  = S + 16*na;      // 16n, dead after agg1
  float* h1   = S + 32*na;      // 16n, dead after pre2
  float* xl2  = S;              // 32n (over xl1/xr1)
  float* xr2  = S + 48*na;      // 32n
  float* asrc = S + 32*na;      // 2n  (over h1, dead)
  float* bdst = S + 34*na;      // 2n

  dim3 blk(256);
  dim3 ge((E + 255)/256), gn((n + 255)/256);
  dim3 ge4(((E + 3)/4 + 255)/256), gn4(((size_t)4*n + 255)/256);

  hipMemsetAsync(deg, 0, (size_t)n*sizeof(int), stream);
  k_wcomb<<<1,192,0,stream>>>(w_e1,b_e1,w_e2,b_e2,wc,bc);

  // ---- CSR build: hist -> 3-stage scan -> eid scatter -> gather materialize ----
  k_hist<<<ge4,blk,0,stream>>>(ei + E, deg, E);
  k_scan1<<<nb1,256,0,stream>>>(deg,bsum,n);
  k_scan2<<<1,1024,0,stream>>>(bsum,boffs,nb1);
  k_scan3<<<nb1,256,0,stream>>>(deg,boffs,rowstart,wptr,n);
  k_scatter_eid<<<ge,blk,0,stream>>>(ei + E, wptr, perm, E);
  k_material<<<ge,blk,0,stream>>>(perm, ei, ew, ce, csr, E);

  // ---- GATv2 layer 1 (in 8, C=4) ----
  k_pre1<<<gn,blk,0,stream>>>(x,w_init,b_init,w1l,b1l,w1r,b1r,xl1,xr1,n);
  k_agg1<<<gn4,blk,0,stream>>>(rowstart,csr,xl1,xr1,w1e,att1,bias1,h1,n);

  // ---- GATv2 layer 2 (in 16, C=8) + fused fc/edge-MLP node terms ----
  k_pre2<<<gn,blk,0,stream>>>(h1,w2l,b2l,w2r,b2r,xl2,xr2,n);
  k_agg2f<<<gn4,blk,0,stream>>>(rowstart,csr,xl2,xr2,w2e,att2,bias2,w_fc,b_fc,wc,asrc,bdst,n);

  // ---- edge scores ----
  k_edge_final<<<ge,blk,0,stream>>>(ei,ew,ce,asrc,bdst,wc,bc,(float2*)d_out,E);
}

// Round 7
// 690.274 us; speedup vs baseline: 1.9623x; 1.4040x over previous
//
#include <hip/hip_runtime.h>

// KEPCE_GAT r7: CSR build via deterministic counting-sort partition
// (LDS histograms + hierarchical scan; zero scattered global stores,
// zero global atomic hot spots). Agg: thread-per-(node,head) online
// softmax with fused fc/edge-MLP epilogue.

__device__ __forceinline__ float lrelu(float v){ return v > 0.f ? v : 0.2f*v; }

#define BSH   7        // bucket = dst >> 7  (128 dsts/bucket)
#define TTILE 16384    // edges per partition tile (256 thr x 64)

// Fold edge MLP: Wc[66,2] = w_e1[66,32] @ w_e2[32,2]; bc[2] = b_e1@w_e2 + b_e2.
__global__ void k_wcomb(const float* __restrict__ we1, const float* __restrict__ be1,
                        const float* __restrict__ we2, const float* __restrict__ be2,
                        float* __restrict__ wc, float* __restrict__ bc){
  int t = threadIdx.x;
  if (t < 132){
    int i = t >> 1, k = t & 1;
    float acc = 0.f;
    for (int j = 0; j < 32; ++j) acc += we1[i*32+j]*we2[j*2+k];
    wc[t] = acc;
  } else if (t < 134){
    int k = t - 132;
    float acc = be2[k];
    for (int j = 0; j < 32; ++j) acc += be1[j]*we2[j*2+k];
    bc[k] = acc;
  }
}

// In-degree histogram, 4 edges/thread.
__global__ void k_hist(const int* __restrict__ dst, int* __restrict__ deg, int E){
  int t = blockIdx.x*blockDim.x + threadIdx.x;
  int base = t << 2;
  if (base + 4 <= E){
    int4 d = *(const int4*)(dst + base);
    atomicAdd(&deg[d.x], 1); atomicAdd(&deg[d.y], 1);
    atomicAdd(&deg[d.z], 1); atomicAdd(&deg[d.w], 1);
  } else {
    for (int k = base; k < E; ++k) atomicAdd(&deg[dst[k]], 1);
  }
}

// Scan stage 1: per-256-block sums.
__global__ void k_scan1(const int* __restrict__ src, int* __restrict__ bsum, int n){
  __shared__ int lds[256];
  int t = threadIdx.x, k = blockIdx.x*256 + t;
  lds[t] = (k < n) ? src[k] : 0;
  __syncthreads();
  #pragma unroll
  for (int off = 1; off < 256; off <<= 1){
    int u = (t >= off) ? lds[t-off] : 0;
    __syncthreads();
    lds[t] += u;
    __syncthreads();
  }
  if (t == 255) bsum[blockIdx.x] = lds[255];
}

// Scan stage 2: exclusive scan of block sums (nb <= 1024). One block.
__global__ void k_scan2(const int* __restrict__ bsum, int* __restrict__ boffs, int nb){
  __shared__ int lds[1024];
  int t = threadIdx.x;
  int v = (t < nb) ? bsum[t] : 0;
  lds[t] = v;
  __syncthreads();
  #pragma unroll
  for (int off = 1; off < 1024; off <<= 1){
    int u = (t >= off) ? lds[t-off] : 0;
    __syncthreads();
    lds[t] += u;
    __syncthreads();
  }
  if (t < nb) boffs[t] = lds[t] - v;
}

// Scan stage 3 (rowstart variant): exclusive scan + final total element.
__global__ void k_scan3r(const int* __restrict__ src, const int* __restrict__ boffs,
                         int* __restrict__ rowstart, int n){
  __shared__ int lds[256];
  int t = threadIdx.x, k = blockIdx.x*256 + t;
  int v = (k < n) ? src[k] : 0;
  lds[t] = v;
  __syncthreads();
  #pragma unroll
  for (int off = 1; off < 256; off <<= 1){
    int u = (t >= off) ? lds[t-off] : 0;
    __syncthreads();
    lds[t] += u;
    __syncthreads();
  }
  if (k < n){
    int excl = boffs[blockIdx.x] + lds[t] - v;
    rowstart[k] = excl;
    if (k == n-1) rowstart[n] = excl + v;
  }
}

// Scan stage 3 (generic): exclusive scan into out.
__global__ void k_scan3g(const int* __restrict__ src, const int* __restrict__ boffs,
                         int* __restrict__ out, int n){
  __shared__ int lds[256];
  int t = threadIdx.x, k = blockIdx.x*256 + t;
  int v = (k < n) ? src[k] : 0;
  lds[t] = v;
  __syncthreads();
  #pragma unroll
  for (int off = 1; off < 256; off <<= 1){
    int u = (t >= off) ? lds[t-off] : 0;
    __syncthreads();
    lds[t] += u;
    __syncthreads();
  }
  if (k < n) out[k] = boffs[blockIdx.x] + lds[t] - v;
}

// Per-tile bucket histogram (LDS) -> hmat[bucket][tile] (bucket-major).
__global__ void k_histT(const int* __restrict__ dst, int* __restrict__ hmat,
                        int E, int ntiles, int nbk){
  __shared__ int cnt[1024];
  int tile = blockIdx.x, lt = threadIdx.x;
  for (int b = lt; b < nbk; b += 256) cnt[b] = 0;
  __syncthreads();
  int tb = tile*TTILE;
  #pragma unroll 4
  for (int r = 0; r < TTILE/256; ++r){
    int e = tb + r*256 + lt;
    if (e < E) atomicAdd(&cnt[dst[e] >> BSH], 1);
  }
  __syncthreads();
  for (int b = lt; b < nbk; b += 256) hmat[(size_t)b*ntiles + tile] = cnt[b];
}

// Partition pass: streaming re-read of edge arrays; LDS ranks; write int4
// records {src,w,c,dst} to exact (bucket,tile) offsets -> bucket-grouped tmp.
__global__ void k_partition(const int* __restrict__ ei, const float* __restrict__ ew,
                            const float* __restrict__ ce, const int* __restrict__ gofs,
                            int4* __restrict__ tmp, int E, int ntiles, int nbk){
  __shared__ int cnt[1024];
  __shared__ int base[1024];
  int tile = blockIdx.x, lt = threadIdx.x;
  for (int b = lt; b < nbk; b += 256){
    cnt[b] = 0;
    base[b] = gofs[(size_t)b*ntiles + tile];
  }
  __syncthreads();
  int tb = tile*TTILE;
  #pragma unroll 4
  for (int r = 0; r < TTILE/256; ++r){
    int e = tb + r*256 + lt;
    if (e < E){
      int d = ei[E+e];
      int bk = d >> BSH;
      int rk = atomicAdd(&cnt[bk], 1);
      tmp[base[bk] + rk] = make_int4(ei[e], __float_as_int(ew[e]),
                                     __float_as_int(ce[e]), d);
    }
  }
}

// Final per-dst grouping: one block per bucket; LDS cursors seeded from
// rowstart; reads streaming, writes confined to the bucket's contiguous
// CSR window (~65KB) -> dense line fill, zero global atomics.
__global__ void k_binC(const int4* __restrict__ tmp, const int* __restrict__ rowstart,
                       int4* __restrict__ csr, int n){
  __shared__ int cur[1<<BSH];
  int b = blockIdx.x, lt = threadIdx.x;
  int d0 = b << BSH;
  if (lt < (1<<BSH)){
    int d = d0 + lt;
    cur[lt] = (d < n) ? rowstart[d] : 0;
  }
  int segs = rowstart[d0];
  int lim = d0 + (1<<BSH); if (lim > n) lim = n;
  int sege = rowstart[lim];
  __syncthreads();
  for (int j = segs + lt; j < sege; j += 256){
    int4 rec = tmp[j];
    int pos = atomicAdd(&cur[rec.w & ((1<<BSH)-1)], 1);
    csr[pos] = rec;
  }
}

// Fused init+pre layer1: h0 = relu(x@wi+bi) in regs; xl1/xr1 = h0@Wl/Wr + b.
__global__ void k_pre1(const float* __restrict__ x, const float* __restrict__ wi,
                       const float* __restrict__ bi, const float* __restrict__ wl,
                       const float* __restrict__ bl, const float* __restrict__ wr,
                       const float* __restrict__ br, float* __restrict__ xl,
                       float* __restrict__ xr, int n){
  int i = blockIdx.x*blockDim.x + threadIdx.x;
  if (i >= n) return;
  float xi[5];
  #pragma unroll
  for (int j = 0; j < 5; ++j) xi[j] = x[i*5+j];
  float h[8];
  #pragma unroll
  for (int o = 0; o < 8; ++o){
    float acc = bi[o];
    #pragma unroll
    for (int j = 0; j < 5; ++j) acc += xi[j]*wi[j*8+o];
    h[o] = fmaxf(acc, 0.f);
  }
  #pragma unroll
  for (int o = 0; o < 16; ++o){
    float a = bl[o], r = br[o];
    #pragma unroll
    for (int j = 0; j < 8; ++j){ a += h[j]*wl[j*16+o]; r += h[j]*wr[j*16+o]; }
    xl[(size_t)i*16+o] = a;
    xr[(size_t)i*16+o] = r;
  }
}

// xl = hin@Wl+bl, xr = hin@Wr+br (layer2: 16 -> 32).
__global__ void k_pre2(const float* __restrict__ hin,
                       const float* __restrict__ wl, const float* __restrict__ bl,
                       const float* __restrict__ wr, const float* __restrict__ br,
                       float* __restrict__ xl, float* __restrict__ xr, int n){
  int i = blockIdx.x*blockDim.x + threadIdx.x;
  if (i >= n) return;
  float h[16];
  #pragma unroll
  for (int j = 0; j < 16; ++j) h[j] = hin[(size_t)i*16+j];
  #pragma unroll
  for (int o = 0; o < 32; ++o){
    float a = bl[o], r = br[o];
    #pragma unroll
    for (int j = 0; j < 16; ++j){ a += h[j]*wl[j*32+o]; r += h[j]*wr[j*32+o]; }
    xl[(size_t)i*32+o] = a;
    xr[(size_t)i*32+o] = r;
  }
}

// Layer-1 aggregation: 4 threads/node (one per head), C=4. Online softmax,
// edge-attr mean in-loop, self-loop last. h1 = relu(num/den + bias).
__global__ void k_agg1(const int* __restrict__ rowstart, const int4* __restrict__ csr,
                       const float* __restrict__ xl, const float* __restrict__ xr,
                       const float* __restrict__ we, const float* __restrict__ att,
                       const float* __restrict__ bias, float* __restrict__ hout, int n){
  constexpr int C = 4, HC = 16;
  int t = blockIdx.x*blockDim.x + threadIdx.x;
  int i = t >> 2, head = t & 3;
  if (i >= n) return;
  float weA[C], weB[C], AT[C], BS[C];
  #pragma unroll
  for (int c = 0; c < C; ++c){
    int o = head*C + c;
    weA[c] = we[o]; weB[c] = we[HC+o]; AT[c] = att[o]; BS[c] = bias[o];
  }
  float XR[C];
  {
    float4 b = *(const float4*)(xr + (size_t)i*HC + head*C);
    XR[0]=b.x; XR[1]=b.y; XR[2]=b.z; XR[3]=b.w;
  }
  float m = -3.0e38f, den = 0.f, sw = 0.f, sc = 0.f;
  float num[C] = {0.f,0.f,0.f,0.f};
  int rs = rowstart[i], re = rowstart[i+1];
  int j = rs;
  for (; j + 2 <= re; j += 2){
    int4 pa = csr[j], pb = csr[j+1];
    float4 qa = *(const float4*)(xl + (size_t)pa.x*HC + head*C);
    float4 qb = *(const float4*)(xl + (size_t)pb.x*HC + head*C);
    float f0a = __int_as_float(pa.y), f1a = __int_as_float(pa.z);
    float f0b = __int_as_float(pb.y), f1b = __int_as_float(pb.z);
    sw += f0a + f0b; sc += f1a + f1b;
    float XA[C] = {qa.x,qa.y,qa.z,qa.w};
    float XB[C] = {qb.x,qb.y,qb.z,qb.w};
    float aa = 0.f, ab = 0.f;
    #pragma unroll
    for (int c = 0; c < C; ++c) aa += AT[c]*lrelu(XA[c] + XR[c] + f0a*weA[c] + f1a*weB[c]);
    #pragma unroll
    for (int c = 0; c < C; ++c) ab += AT[c]*lrelu(XB[c] + XR[c] + f0b*weA[c] + f1b*weB[c]);
    float nm = fmaxf(m, aa);
    float r = __expf(m - nm), ex = __expf(aa - nm);
    den = den*r + ex;
    #pragma unroll
    for (int c = 0; c < C; ++c) num[c] = num[c]*r + ex*XA[c];
    m = nm;
    nm = fmaxf(m, ab); r = __expf(m - nm); ex = __expf(ab - nm);
    den = den*r + ex;
    #pragma unroll
    for (int c = 0; c < C; ++c) num[c] = num[c]*r + ex*XB[c];
    m = nm;
  }
  if (j < re){
    int4 pa = csr[j];
    float4 qa = *(const float4*)(xl + (size_t)pa.x*HC + head*C);
    float f0a = __int_as_float(pa.y), f1a = __int_as_float(pa.z);
    sw += f0a; sc += f1a;
    float XA[C] = {qa.x,qa.y,qa.z,qa.w};
    float aa = 0.f;
    #pragma unroll
    for (int c = 0; c < C; ++c) aa += AT[c]*lrelu(XA[c] + XR[c] + f0a*weA[c] + f1a*weB[c]);
    float nm = fmaxf(m, aa);
    float r = __expf(m - nm), ex = __expf(aa - nm);
    den = den*r + ex;
    #pragma unroll
    for (int c = 0; c < C; ++c) num[c] = num[c]*r + ex*XA[c];
    m = nm;
  }
  float cf = fmaxf((float)(re - rs), 1.f);
  float la0 = sw/cf, la1 = sc/cf;
  float4 qs = *(const float4*)(xl + (size_t)i*HC + head*C);
  float XS[C] = {qs.x,qs.y,qs.z,qs.w};
  float as = 0.f;
  #pragma unroll
  for (int c = 0; c < C; ++c) as += AT[c]*lrelu(XS[c] + XR[c] + la0*weA[c] + la1*weB[c]);
  float nm = fmaxf(m, as);
  float r = __expf(m - nm), ex = __expf(as - nm);
  den = den*r + ex;
  #pragma unroll
  for (int c = 0; c < C; ++c) num[c] = num[c]*r + ex*XS[c];
  float inv = 1.f/den;
  #pragma unroll
  for (int c = 0; c < C; ++c)
    hout[(size_t)i*HC + head*C + c] = fmaxf(num[c]*inv + BS[c], 0.f);
}

// Layer-2 aggregation (C=8) with fc + folded edge-MLP epilogue fused via LDS.
__global__ void k_agg2f(const int* __restrict__ rowstart, const int4* __restrict__ csr,
                        const float* __restrict__ xl, const float* __restrict__ xr,
                        const float* __restrict__ we, const float* __restrict__ att,
                        const float* __restrict__ bias, const float* __restrict__ wfc,
                        const float* __restrict__ bfc, const float* __restrict__ wc,
                        float* __restrict__ asrc, float* __restrict__ bdst, int n){
  constexpr int C = 8, HC = 32;
  __shared__ float s_h[64*33];
  __shared__ float s_w[1024];
  __shared__ float s_wc[134];
  int lt = threadIdx.x;
  for (int k = lt; k < 1024; k += 256) s_w[k] = wfc[k];
  if (lt < 134) s_wc[lt] = wc[lt];
  int t = blockIdx.x*blockDim.x + lt;
  int i = t >> 2, head = t & 3;
  bool valid = i < n;
  int ic = valid ? i : 0;
  float weA[C], weB[C], AT[C], BS[C];
  #pragma unroll
  for (int c = 0; c < C; ++c){
    int o = head*C + c;
    weA[c] = we[o]; weB[c] = we[HC+o]; AT[c] = att[o]; BS[c] = bias[o];
  }
  float XR[C];
  {
    const float4* pr = (const float4*)(xr + (size_t)ic*HC + head*C);
    float4 b0 = pr[0], b1 = pr[1];
    XR[0]=b0.x; XR[1]=b0.y; XR[2]=b0.z; XR[3]=b0.w;
    XR[4]=b1.x; XR[5]=b1.y; XR[6]=b1.z; XR[7]=b1.w;
  }
  float m = -3.0e38f, den = 0.f, sw = 0.f, sc = 0.f;
  float num[C] = {0.f,0.f,0.f,0.f,0.f,0.f,0.f,0.f};
  int rs = 0, re = 0;
  if (valid){ rs = rowstart[i]; re = rowstart[i+1]; }
  int j = rs;
  for (; j + 2 <= re; j += 2){
    int4 pa = csr[j], pb = csr[j+1];
    const float4* qa = (const float4*)(xl + (size_t)pa.x*HC + head*C);
    const float4* qb = (const float4*)(xl + (size_t)pb.x*HC + head*C);
    float4 a0 = qa[0], a1 = qa[1], b0 = qb[0], b1 = qb[1];
    float f0a = __int_as_float(pa.y), f1a = __int_as_float(pa.z);
    float f0b = __int_as_float(pb.y), f1b = __int_as_float(pb.z);
    sw += f0a + f0b; sc += f1a + f1b;
    float XA[C] = {a0.x,a0.y,a0.z,a0.w,a1.x,a1.y,a1.z,a1.w};
    float XB[C] = {b0.x,b0.y,b0.z,b0.w,b1.x,b1.y,b1.z,b1.w};
    float aa = 0.f, ab = 0.f;
    #pragma unroll
    for (int c = 0; c < C; ++c) aa += AT[c]*lrelu(XA[c] + XR[c] + f0a*weA[c] + f1a*weB[c]);
    #pragma unroll
    for (int c = 0; c < C; ++c) ab += AT[c]*lrelu(XB[c] + XR[c] + f0b*weA[c] + f1b*weB[c]);
    float nm = fmaxf(m, aa);
    float r = __expf(m - nm), ex = __expf(aa - nm);
    den = den*r + ex;
    #pragma unroll
    for (int c = 0; c < C; ++c) num[c] = num[c]*r + ex*XA[c];
    m = nm;
    nm = fmaxf(m, ab); r = __expf(m - nm); ex = __expf(ab - nm);
    den = den*r + ex;
    #pragma unroll
    for (int c = 0; c < C; ++c) num[c] = num[c]*r + ex*XB[c];
    m = nm;
  }
  if (j < re){
    int4 pa = csr[j];
    const float4* qa = (const float4*)(xl + (size_t)pa.x*HC + head*C);
    float4 a0 = qa[0], a1 = qa[1];
    float f0a = __int_as_float(pa.y), f1a = __int_as_float(pa.z);
    sw += f0a; sc += f1a;
    float XA[C] = {a0.x,a0.y,a0.z,a0.w,a1.x,a1.y,a1.z,a1.w};
    float aa = 0.f;
    #pragma unroll
    for (int c = 0; c < C; ++c) aa += AT[c]*lrelu(XA[c] + XR[c] + f0a*weA[c] + f1a*weB[c]);
    float nm = fmaxf(m, aa);
    float r = __expf(m - nm), ex = __expf(aa - nm);
    den = den*r + ex;
    #pragma unroll
    for (int c = 0; c < C; ++c) num[c] = num[c]*r + ex*XA[c];
    m = nm;
  }
  float out8[C];
  if (valid){
    float cf = fmaxf((float)(re - rs), 1.f);
    float la0 = sw/cf, la1 = sc/cf;
    const float4* pl = (const float4*)(xl + (size_t)i*HC + head*C);
    float4 s0 = pl[0], s1 = pl[1];
    float XS[C] = {s0.x,s0.y,s0.z,s0.w,s1.x,s1.y,s1.z,s1.w};
    float as = 0.f;
    #pragma unroll
    for (int c = 0; c < C; ++c) as += AT[c]*lrelu(XS[c] + XR[c] + la0*weA[c] + la1*weB[c]);
    float nm = fmaxf(m, as);
    float r = __expf(m - nm), ex = __expf(as - nm);
    den = den*r + ex;
    #pragma unroll
    for (int c = 0; c < C; ++c) num[c] = num[c]*r + ex*XS[c];
    float inv = 1.f/den;
    #pragma unroll
    for (int c = 0; c < C; ++c) out8[c] = fmaxf(num[c]*inv + BS[c], 0.f);
  } else {
    #pragma unroll
    for (int c = 0; c < C; ++c) out8[c] = 0.f;
  }
  int ln = lt >> 2;
  #pragma unroll
  for (int c = 0; c < C; ++c) s_h[ln*33 + head*C + c] = out8[c];
  __syncthreads();
  float hl[32];
  #pragma unroll
  for (int j2 = 0; j2 < 32; ++j2) hl[j2] = s_h[ln*33 + j2];
  float pa0=0.f, pa1=0.f, pb0=0.f, pb1=0.f;
  #pragma unroll
  for (int oc = 0; oc < 8; ++oc){
    int o = head*8 + oc;
    float acc = bfc[o];
    #pragma unroll
    for (int j2 = 0; j2 < 32; ++j2) acc += hl[j2]*s_w[j2*32+o];
    float f = fmaxf(acc, 0.f);
    pa0 += f*s_wc[(2+o)*2];  pa1 += f*s_wc[(2+o)*2+1];
    pb0 += f*s_wc[(34+o)*2]; pb1 += f*s_wc[(34+o)*2+1];
  }
  pa0 += __shfl_xor(pa0,1); pa0 += __shfl_xor(pa0,2);
  pa1 += __shfl_xor(pa1,1); pa1 += __shfl_xor(pa1,2);
  pb0 += __shfl_xor(pb0,1); pb0 += __shfl_xor(pb0,2);
  pb1 += __shfl_xor(pb1,1); pb1 += __shfl_xor(pb1,2);
  if (valid){
    if (head == 0)      ((float2*)asrc)[i] = make_float2(pa0, pa1);
    else if (head == 1) ((float2*)bdst)[i] = make_float2(pb0, pb1);
  }
}

// out[e] = ef[e]@Wc[0:2] + asrc[src] + bdst[dst] + bc  (float2 store)
__global__ void k_edge_final(const int* __restrict__ ei, const float* __restrict__ ew,
                             const float* __restrict__ ce, const float* __restrict__ asrc,
                             const float* __restrict__ bdst, const float* __restrict__ wc,
                             const float* __restrict__ bc, float2* __restrict__ out, int E){
  int e = blockIdx.x*blockDim.x + threadIdx.x;
  if (e >= E) return;
  int s = ei[e], d = ei[E+e];
  float f0 = ew[e], f1 = ce[e];
  float2 a = ((const float2*)asrc)[s];
  float2 b = ((const float2*)bdst)[d];
  out[e] = make_float2(f0*wc[0] + f1*wc[2] + a.x + b.x + bc[0],
                       f0*wc[1] + f1*wc[3] + a.y + b.y + bc[1]);
}

extern "C" void kernel_launch(void* const* d_in, const int* in_sizes, int n_in,
                              void* d_out, int out_size, void* d_ws, size_t ws_size,
                              hipStream_t stream){
  const float* x     = (const float*)d_in[0];
  const int*   ei    = (const int*)  d_in[1];
  const float* ew    = (const float*)d_in[2];
  const float* ce    = (const float*)d_in[3];
  const float* w_init= (const float*)d_in[4];
  const float* b_init= (const float*)d_in[5];
  const float* w1l   = (const float*)d_in[6];
  const float* b1l   = (const float*)d_in[7];
  const float* w1r   = (const float*)d_in[8];
  const float* b1r   = (const float*)d_in[9];
  const float* w1e   = (const float*)d_in[10];
  const float* att1  = (const float*)d_in[11];
  const float* bias1 = (const float*)d_in[12];
  const float* w2l   = (const float*)d_in[13];
  const float* b2l   = (const float*)d_in[14];
  const float* w2r   = (const float*)d_in[15];
  const float* b2r   = (const float*)d_in[16];
  const float* w2e   = (const float*)d_in[17];
  const float* att2  = (const float*)d_in[18];
  const float* bias2 = (const float*)d_in[19];
  const float* w_fc  = (const float*)d_in[20];
  const float* b_fc  = (const float*)d_in[21];
  const float* w_e1  = (const float*)d_in[22];
  const float* b_e1  = (const float*)d_in[23];
  const float* w_e2  = (const float*)d_in[24];
  const float* b_e2  = (const float*)d_in[25];

  const int n = in_sizes[0]/5;     // 100000
  const int E = in_sizes[2];       // 3200000
  const int nb1    = (n + 255) >> 8;              // deg-scan blocks
  const int ntiles = (E + TTILE - 1) / TTILE;     // 196
  const int nbk    = (n + (1<<BSH) - 1) >> BSH;   // 782 buckets (<=1024)
  const int M      = nbk * ntiles;                // hist matrix size
  const int nbA    = (M + 255) >> 8;              // hmat-scan blocks (<=1024)

  // ---- workspace layout: 128B-aligned (32 x 4B units) ----
  int*   W32 = (int*)d_ws;
  float* Wf  = (float*)d_ws;
  size_t off = 0;
  auto nxt = [&off](size_t cnt){ size_t p = off; off += (cnt + 31) & ~(size_t)31; return p; };
  int*   deg      = W32 + nxt(n);
  int*   rowstart = W32 + nxt((size_t)n + 1);
  int*   bsum     = W32 + nxt(nb1 > nbA ? nb1 : nbA);
  int*   boffs    = W32 + nxt(nb1 > nbA ? nb1 : nbA);
  int*   hmat     = W32 + nxt(M);
  int*   gofs     = W32 + nxt(M);
  float* wc       = Wf  + nxt(160);
  float* bc       = wc + 132;
  int4*  csr      = (int4*)(W32 + nxt((size_t)4*E));
  // big region: tmp (4E ints, dead after binC) aliased with node scratch.
  size_t na = ((size_t)n + 31) & ~(size_t)31;
  size_t bigsz = (size_t)4*E > 80*na ? (size_t)4*E : 80*na;
  float* S    = Wf + nxt(bigsz);
  int4*  tmp  = (int4*)S;
  float* xl1  = S;              // 16n, dead after agg1
  float* xr1  = S + 16*na;      // 16n, dead after agg1
  float* h1   = S + 32*na;      // 16n, dead after pre2
  float* xl2  = S;              // 32n (over xl1/xr1)
  float* xr2  = S + 48*na;      // 32n
  float* asrc = S + 32*na;      // 2n  (over h1, dead)
  float* bdst = S + 34*na;      // 2n

  dim3 blk(256);
  dim3 ge((E + 255)/256), gn((n + 255)/256);
  dim3 ge4(((E + 3)/4 + 255)/256), gn4(((size_t)4*n + 255)/256);

  hipMemsetAsync(deg, 0, (size_t)n*sizeof(int), stream);
  k_wcomb<<<1,192,0,stream>>>(w_e1,b_e1,w_e2,b_e2,wc,bc);

  // ---- rowstart: deg histogram + 3-stage scan ----
  k_hist<<<ge4,blk,0,stream>>>(ei + E, deg, E);
  k_scan1<<<nb1,256,0,stream>>>(deg,bsum,n);
  k_scan2<<<1,1024,0,stream>>>(bsum,boffs,nb1);
  k_scan3r<<<nb1,256,0,stream>>>(deg,boffs,rowstart,n);

  // ---- counting-sort CSR build ----
  k_histT<<<ntiles,256,0,stream>>>(ei + E, hmat, E, ntiles, nbk);
  k_scan1<<<nbA,256,0,stream>>>(hmat,bsum,M);
  k_scan2<<<1,1024,0,stream>>>(bsum,boffs,nbA);
  k_scan3g<<<nbA,256,0,stream>>>(hmat,boffs,gofs,M);
  k_partition<<<ntiles,256,0,stream>>>(ei,ew,ce,gofs,tmp,E,ntiles,nbk);
  k_binC<<<nbk,256,0,stream>>>(tmp,rowstart,csr,n);

  // ---- GATv2 layer 1 (in 8, C=4) ----
  k_pre1<<<gn,blk,0,stream>>>(x,w_init,b_init,w1l,b1l,w1r,b1r,xl1,xr1,n);
  k_agg1<<<gn4,blk,0,stream>>>(rowstart,csr,xl1,xr1,w1e,att1,bias1,h1,n);

  // ---- GATv2 layer 2 (in 16, C=8) + fused fc/edge-MLP node terms ----
  k_pre2<<<gn,blk,0,stream>>>(h1,w2l,b2l,w2r,b2r,xl2,xr2,n);
  k_agg2f<<<gn4,blk,0,stream>>>(rowstart,csr,xl2,xr2,w2e,att2,bias2,w_fc,b_fc,wc,asrc,bdst,n);

  // ---- edge scores ----
  k_edge_final<<<ge,blk,0,stream>>>(ei,ew,ce,asrc,bdst,wc,bc,(float2*)d_out,E);
}

// Round 8
// 569.208 us; speedup vs baseline: 2.3796x; 1.2127x over previous
//
#include <hip/hip_runtime.h>

// KEPCE_GAT r8: zero global atomics anywhere. CSR build = LDS counting sort:
//   histT (per-tile LDS bucket hist) -> hierarchical scan -> partition
//   (bucket-major tmp) -> k_bucket (per-bucket LDS dst-hist + scan ->
//   rowstart + exact CSR placement, all writes window-local).
// Agg: thread-per-(node,head) online softmax, fused fc/edge-MLP epilogue.

__device__ __forceinline__ float lrelu(float v){ return v > 0.f ? v : 0.2f*v; }

#define BSH   7        // bucket = dst >> 7  (128 dsts/bucket)
#define BKN   (1<<BSH)
#define TTILE 16384    // edges per partition tile (256 thr x 64)

// Fold edge MLP: Wc[66,2] = w_e1[66,32] @ w_e2[32,2]; bc[2] = b_e1@w_e2 + b_e2.
__global__ void k_wcomb(const float* __restrict__ we1, const float* __restrict__ be1,
                        const float* __restrict__ we2, const float* __restrict__ be2,
                        float* __restrict__ wc, float* __restrict__ bc){
  int t = threadIdx.x;
  if (t < 132){
    int i = t >> 1, k = t & 1;
    float acc = 0.f;
    for (int j = 0; j < 32; ++j) acc += we1[i*32+j]*we2[j*2+k];
    wc[t] = acc;
  } else if (t < 134){
    int k = t - 132;
    float acc = be2[k];
    for (int j = 0; j < 32; ++j) acc += be1[j]*we2[j*2+k];
    bc[k] = acc;
  }
}

// Scan stage 1: per-256-block sums.
__global__ void k_scan1(const int* __restrict__ src, int* __restrict__ bsum, int n){
  __shared__ int lds[256];
  int t = threadIdx.x, k = blockIdx.x*256 + t;
  lds[t] = (k < n) ? src[k] : 0;
  __syncthreads();
  #pragma unroll
  for (int off = 1; off < 256; off <<= 1){
    int u = (t >= off) ? lds[t-off] : 0;
    __syncthreads();
    lds[t] += u;
    __syncthreads();
  }
  if (t == 255) bsum[blockIdx.x] = lds[255];
}

// Scan stage 2: exclusive scan of block sums (nb <= 1024). One block.
__global__ void k_scan2(const int* __restrict__ bsum, int* __restrict__ boffs, int nb){
  __shared__ int lds[1024];
  int t = threadIdx.x;
  int v = (t < nb) ? bsum[t] : 0;
  lds[t] = v;
  __syncthreads();
  #pragma unroll
  for (int off = 1; off < 1024; off <<= 1){
    int u = (t >= off) ? lds[t-off] : 0;
    __syncthreads();
    lds[t] += u;
    __syncthreads();
  }
  if (t < nb) boffs[t] = lds[t] - v;
}

// Scan stage 3: exclusive scan into out.
__global__ void k_scan3g(const int* __restrict__ src, const int* __restrict__ boffs,
                         int* __restrict__ out, int n){
  __shared__ int lds[256];
  int t = threadIdx.x, k = blockIdx.x*256 + t;
  int v = (k < n) ? src[k] : 0;
  lds[t] = v;
  __syncthreads();
  #pragma unroll
  for (int off = 1; off < 256; off <<= 1){
    int u = (t >= off) ? lds[t-off] : 0;
    __syncthreads();
    lds[t] += u;
    __syncthreads();
  }
  if (k < n) out[k] = boffs[blockIdx.x] + lds[t] - v;
}

// Per-tile bucket histogram (LDS) -> hmat[bucket][tile] (bucket-major).
__global__ void k_histT(const int* __restrict__ dst, int* __restrict__ hmat,
                        int E, int ntiles, int nbk){
  __shared__ int cnt[1024];
  int tile = blockIdx.x, lt = threadIdx.x;
  for (int b = lt; b < nbk; b += 256) cnt[b] = 0;
  __syncthreads();
  int tb = tile*TTILE;
  #pragma unroll 4
  for (int r = 0; r < TTILE/256; ++r){
    int e = tb + r*256 + lt;
    if (e < E) atomicAdd(&cnt[dst[e] >> BSH], 1);
  }
  __syncthreads();
  for (int b = lt; b < nbk; b += 256) hmat[(size_t)b*ntiles + tile] = cnt[b];
}

// Partition pass: streaming re-read of edge arrays; LDS ranks; write int4
// records {src,w,c,dst} to exact (bucket,tile) offsets -> bucket-grouped tmp.
__global__ void k_partition(const int* __restrict__ ei, const float* __restrict__ ew,
                            const float* __restrict__ ce, const int* __restrict__ gofs,
                            int4* __restrict__ tmp, int E, int ntiles, int nbk){
  __shared__ int cnt[1024];
  __shared__ int base[1024];
  int tile = blockIdx.x, lt = threadIdx.x;
  for (int b = lt; b < nbk; b += 256){
    cnt[b] = 0;
    base[b] = gofs[(size_t)b*ntiles + tile];
  }
  __syncthreads();
  int tb = tile*TTILE;
  #pragma unroll 4
  for (int r = 0; r < TTILE/256; ++r){
    int e = tb + r*256 + lt;
    if (e < E){
      int d = ei[E+e];
      int bk = d >> BSH;
      int rk = atomicAdd(&cnt[bk], 1);
      tmp[base[bk] + rk] = make_int4(ei[e], __float_as_int(ew[e]),
                                     __float_as_int(ce[e]), d);
    }
  }
}

// Per-bucket finalize: LDS dst-histogram of the bucket window (read 1),
// 128-wide LDS exclusive scan + bucket base -> rowstart (coalesced write),
// then exact placement via LDS cursors (read 2, window L2-hot).
// Eliminates the global-atomic degree histogram entirely.
__global__ void k_bucket(const int4* __restrict__ tmp, const int* __restrict__ gofs,
                         int* __restrict__ rowstart, int4* __restrict__ csr,
                         int n, int E, int ntiles, int nbk){
  __shared__ int cnt[BKN];
  __shared__ int sc[BKN];
  __shared__ int cur[BKN];
  int b = blockIdx.x, lt = threadIdx.x;
  int d0 = b << BSH;
  int segs = gofs[(size_t)b*ntiles];
  int sege = (b+1 < nbk) ? gofs[(size_t)(b+1)*ntiles] : E;
  if (lt < BKN) cnt[lt] = 0;
  __syncthreads();
  for (int j = segs + lt; j < sege; j += 256)
    atomicAdd(&cnt[tmp[j].w & (BKN-1)], 1);
  __syncthreads();
  if (lt < BKN) sc[lt] = cnt[lt];
  __syncthreads();
  #pragma unroll
  for (int off = 1; off < BKN; off <<= 1){
    int u = (lt >= off && lt < BKN) ? sc[lt-off] : 0;
    __syncthreads();
    if (lt < BKN) sc[lt] += u;
    __syncthreads();
  }
  if (lt < BKN){
    int excl = segs + sc[lt] - cnt[lt];
    cur[lt] = excl;
    int d = d0 + lt;
    if (d < n) rowstart[d] = excl;
  }
  if (b == 0 && lt == 0) rowstart[n] = E;
  __syncthreads();
  for (int j = segs + lt; j < sege; j += 256){
    int4 rec = tmp[j];
    int pos = atomicAdd(&cur[rec.w & (BKN-1)], 1);
    csr[pos] = rec;
  }
}

// Fused init+pre layer1: h0 = relu(x@wi+bi) in regs; xl1/xr1 = h0@Wl/Wr + b.
__global__ void k_pre1(const float* __restrict__ x, const float* __restrict__ wi,
                       const float* __restrict__ bi, const float* __restrict__ wl,
                       const float* __restrict__ bl, const float* __restrict__ wr,
                       const float* __restrict__ br, float* __restrict__ xl,
                       float* __restrict__ xr, int n){
  int i = blockIdx.x*blockDim.x + threadIdx.x;
  if (i >= n) return;
  float xi[5];
  #pragma unroll
  for (int j = 0; j < 5; ++j) xi[j] = x[i*5+j];
  float h[8];
  #pragma unroll
  for (int o = 0; o < 8; ++o){
    float acc = bi[o];
    #pragma unroll
    for (int j = 0; j < 5; ++j) acc += xi[j]*wi[j*8+o];
    h[o] = fmaxf(acc, 0.f);
  }
  #pragma unroll
  for (int o = 0; o < 16; ++o){
    float a = bl[o], r = br[o];
    #pragma unroll
    for (int j = 0; j < 8; ++j){ a += h[j]*wl[j*16+o]; r += h[j]*wr[j*16+o]; }
    xl[(size_t)i*16+o] = a;
    xr[(size_t)i*16+o] = r;
  }
}

// xl = hin@Wl+bl, xr = hin@Wr+br (layer2: 16 -> 32).
__global__ void k_pre2(const float* __restrict__ hin,
                       const float* __restrict__ wl, const float* __restrict__ bl,
                       const float* __restrict__ wr, const float* __restrict__ br,
                       float* __restrict__ xl, float* __restrict__ xr, int n){
  int i = blockIdx.x*blockDim.x + threadIdx.x;
  if (i >= n) return;
  float h[16];
  #pragma unroll
  for (int j = 0; j < 16; ++j) h[j] = hin[(size_t)i*16+j];
  #pragma unroll
  for (int o = 0; o < 32; ++o){
    float a = bl[o], r = br[o];
    #pragma unroll
    for (int j = 0; j < 16; ++j){ a += h[j]*wl[j*32+o]; r += h[j]*wr[j*32+o]; }
    xl[(size_t)i*32+o] = a;
    xr[(size_t)i*32+o] = r;
  }
}

// Layer-1 aggregation: 4 threads/node (one per head), C=4. Online softmax,
// edge-attr mean in-loop, self-loop last. h1 = relu(num/den + bias).
__global__ void k_agg1(const int* __restrict__ rowstart, const int4* __restrict__ csr,
                       const float* __restrict__ xl, const float* __restrict__ xr,
                       const float* __restrict__ we, const float* __restrict__ att,
                       const float* __restrict__ bias, float* __restrict__ hout, int n){
  constexpr int C = 4, HC = 16;
  int t = blockIdx.x*blockDim.x + threadIdx.x;
  int i = t >> 2, head = t & 3;
  if (i >= n) return;
  float weA[C], weB[C], AT[C], BS[C];
  #pragma unroll
  for (int c = 0; c < C; ++c){
    int o = head*C + c;
    weA[c] = we[o]; weB[c] = we[HC+o]; AT[c] = att[o]; BS[c] = bias[o];
  }
  float XR[C];
  {
    float4 b = *(const float4*)(xr + (size_t)i*HC + head*C);
    XR[0]=b.x; XR[1]=b.y; XR[2]=b.z; XR[3]=b.w;
  }
  float m = -3.0e38f, den = 0.f, sw = 0.f, sc = 0.f;
  float num[C] = {0.f,0.f,0.f,0.f};
  int rs = rowstart[i], re = rowstart[i+1];
  int j = rs;
  for (; j + 2 <= re; j += 2){
    int4 pa = csr[j], pb = csr[j+1];
    float4 qa = *(const float4*)(xl + (size_t)pa.x*HC + head*C);
    float4 qb = *(const float4*)(xl + (size_t)pb.x*HC + head*C);
    float f0a = __int_as_float(pa.y), f1a = __int_as_float(pa.z);
    float f0b = __int_as_float(pb.y), f1b = __int_as_float(pb.z);
    sw += f0a + f0b; sc += f1a + f1b;
    float XA[C] = {qa.x,qa.y,qa.z,qa.w};
    float XB[C] = {qb.x,qb.y,qb.z,qb.w};
    float aa = 0.f, ab = 0.f;
    #pragma unroll
    for (int c = 0; c < C; ++c) aa += AT[c]*lrelu(XA[c] + XR[c] + f0a*weA[c] + f1a*weB[c]);
    #pragma unroll
    for (int c = 0; c < C; ++c) ab += AT[c]*lrelu(XB[c] + XR[c] + f0b*weA[c] + f1b*weB[c]);
    float nm = fmaxf(m, aa);
    float r = __expf(m - nm), ex = __expf(aa - nm);
    den = den*r + ex;
    #pragma unroll
    for (int c = 0; c < C; ++c) num[c] = num[c]*r + ex*XA[c];
    m = nm;
    nm = fmaxf(m, ab); r = __expf(m - nm); ex = __expf(ab - nm);
    den = den*r + ex;
    #pragma unroll
    for (int c = 0; c < C; ++c) num[c] = num[c]*r + ex*XB[c];
    m = nm;
  }
  if (j < re){
    int4 pa = csr[j];
    float4 qa = *(const float4*)(xl + (size_t)pa.x*HC + head*C);
    float f0a = __int_as_float(pa.y), f1a = __int_as_float(pa.z);
    sw += f0a; sc += f1a;
    float XA[C] = {qa.x,qa.y,qa.z,qa.w};
    float aa = 0.f;
    #pragma unroll
    for (int c = 0; c < C; ++c) aa += AT[c]*lrelu(XA[c] + XR[c] + f0a*weA[c] + f1a*weB[c]);
    float nm = fmaxf(m, aa);
    float r = __expf(m - nm), ex = __expf(aa - nm);
    den = den*r + ex;
    #pragma unroll
    for (int c = 0; c < C; ++c) num[c] = num[c]*r + ex*XA[c];
    m = nm;
  }
  float cf = fmaxf((float)(re - rs), 1.f);
  float la0 = sw/cf, la1 = sc/cf;
  float4 qs = *(const float4*)(xl + (size_t)i*HC + head*C);
  float XS[C] = {qs.x,qs.y,qs.z,qs.w};
  float as = 0.f;
  #pragma unroll
  for (int c = 0; c < C; ++c) as += AT[c]*lrelu(XS[c] + XR[c] + la0*weA[c] + la1*weB[c]);
  float nm = fmaxf(m, as);
  float r = __expf(m - nm), ex = __expf(as - nm);
  den = den*r + ex;
  #pragma unroll
  for (int c = 0; c < C; ++c) num[c] = num[c]*r + ex*XS[c];
  float inv = 1.f/den;
  #pragma unroll
  for (int c = 0; c < C; ++c)
    hout[(size_t)i*HC + head*C + c] = fmaxf(num[c]*inv + BS[c], 0.f);
}

// Layer-2 aggregation (C=8) with fc + folded edge-MLP epilogue fused via LDS.
__global__ void k_agg2f(const int* __restrict__ rowstart, const int4* __restrict__ csr,
                        const float* __restrict__ xl, const float* __restrict__ xr,
                        const float* __restrict__ we, const float* __restrict__ att,
                        const float* __restrict__ bias, const float* __restrict__ wfc,
                        const float* __restrict__ bfc, const float* __restrict__ wc,
                        float* __restrict__ asrc, float* __restrict__ bdst, int n){
  constexpr int C = 8, HC = 32;
  __shared__ float s_h[64*33];
  __shared__ float s_w[1024];
  __shared__ float s_wc[134];
  int lt = threadIdx.x;
  for (int k = lt; k < 1024; k += 256) s_w[k] = wfc[k];
  if (lt < 134) s_wc[lt] = wc[lt];
  int t = blockIdx.x*blockDim.x + lt;
  int i = t >> 2, head = t & 3;
  bool valid = i < n;
  int ic = valid ? i : 0;
  float weA[C], weB[C], AT[C], BS[C];
  #pragma unroll
  for (int c = 0; c < C; ++c){
    int o = head*C + c;
    weA[c] = we[o]; weB[c] = we[HC+o]; AT[c] = att[o]; BS[c] = bias[o];
  }
  float XR[C];
  {
    const float4* pr = (const float4*)(xr + (size_t)ic*HC + head*C);
    float4 b0 = pr[0], b1 = pr[1];
    XR[0]=b0.x; XR[1]=b0.y; XR[2]=b0.z; XR[3]=b0.w;
    XR[4]=b1.x; XR[5]=b1.y; XR[6]=b1.z; XR[7]=b1.w;
  }
  float m = -3.0e38f, den = 0.f, sw = 0.f, sc = 0.f;
  float num[C] = {0.f,0.f,0.f,0.f,0.f,0.f,0.f,0.f};
  int rs = 0, re = 0;
  if (valid){ rs = rowstart[i]; re = rowstart[i+1]; }
  int j = rs;
  for (; j + 2 <= re; j += 2){
    int4 pa = csr[j], pb = csr[j+1];
    const float4* qa = (const float4*)(xl + (size_t)pa.x*HC + head*C);
    const float4* qb = (const float4*)(xl + (size_t)pb.x*HC + head*C);
    float4 a0 = qa[0], a1 = qa[1], b0 = qb[0], b1 = qb[1];
    float f0a = __int_as_float(pa.y), f1a = __int_as_float(pa.z);
    float f0b = __int_as_float(pb.y), f1b = __int_as_float(pb.z);
    sw += f0a + f0b; sc += f1a + f1b;
    float XA[C] = {a0.x,a0.y,a0.z,a0.w,a1.x,a1.y,a1.z,a1.w};
    float XB[C] = {b0.x,b0.y,b0.z,b0.w,b1.x,b1.y,b1.z,b1.w};
    float aa = 0.f, ab = 0.f;
    #pragma unroll
    for (int c = 0; c < C; ++c) aa += AT[c]*lrelu(XA[c] + XR[c] + f0a*weA[c] + f1a*weB[c]);
    #pragma unroll
    for (int c = 0; c < C; ++c) ab += AT[c]*lrelu(XB[c] + XR[c] + f0b*weA[c] + f1b*weB[c]);
    float nm = fmaxf(m, aa);
    float r = __expf(m - nm), ex = __expf(aa - nm);
    den = den*r + ex;
    #pragma unroll
    for (int c = 0; c < C; ++c) num[c] = num[c]*r + ex*XA[c];
    m = nm;
    nm = fmaxf(m, ab); r = __expf(m - nm); ex = __expf(ab - nm);
    den = den*r + ex;
    #pragma unroll
    for (int c = 0; c < C; ++c) num[c] = num[c]*r + ex*XB[c];
    m = nm;
  }
  if (j < re){
    int4 pa = csr[j];
    const float4* qa = (const float4*)(xl + (size_t)pa.x*HC + head*C);
    float4 a0 = qa[0], a1 = qa[1];
    float f0a = __int_as_float(pa.y), f1a = __int_as_float(pa.z);
    sw += f0a; sc += f1a;
    float XA[C] = {a0.x,a0.y,a0.z,a0.w,a1.x,a1.y,a1.z,a1.w};
    float aa = 0.f;
    #pragma unroll
    for (int c = 0; c < C; ++c) aa += AT[c]*lrelu(XA[c] + XR[c] + f0a*weA[c] + f1a*weB[c]);
    float nm = fmaxf(m, aa);
    float r = __expf(m - nm), ex = __expf(aa - nm);
    den = den*r + ex;
    #pragma unroll
    for (int c = 0; c < C; ++c) num[c] = num[c]*r + ex*XA[c];
    m = nm;
  }
  float out8[C];
  if (valid){
    float cf = fmaxf((float)(re - rs), 1.f);
    float la0 = sw/cf, la1 = sc/cf;
    const float4* pl = (const float4*)(xl + (size_t)i*HC + head*C);
    float4 s0 = pl[0], s1 = pl[1];
    float XS[C] = {s0.x,s0.y,s0.z,s0.w,s1.x,s1.y,s1.z,s1.w};
    float as = 0.f;
    #pragma unroll
    for (int c = 0; c < C; ++c) as += AT[c]*lrelu(XS[c] + XR[c] + la0*weA[c] + la1*weB[c]);
    float nm = fmaxf(m, as);
    float r = __expf(m - nm), ex = __expf(as - nm);
    den = den*r + ex;
    #pragma unroll
    for (int c = 0; c < C; ++c) num[c] = num[c]*r + ex*XS[c];
    float inv = 1.f/den;
    #pragma unroll
    for (int c = 0; c < C; ++c) out8[c] = fmaxf(num[c]*inv + BS[c], 0.f);
  } else {
    #pragma unroll
    for (int c = 0; c < C; ++c) out8[c] = 0.f;
  }
  int ln = lt >> 2;
  #pragma unroll
  for (int c = 0; c < C; ++c) s_h[ln*33 + head*C + c] = out8[c];
  __syncthreads();
  float hl[32];
  #pragma unroll
  for (int j2 = 0; j2 < 32; ++j2) hl[j2] = s_h[ln*33 + j2];
  float pa0=0.f, pa1=0.f, pb0=0.f, pb1=0.f;
  #pragma unroll
  for (int oc = 0; oc < 8; ++oc){
    int o = head*8 + oc;
    float acc = bfc[o];
    #pragma unroll
    for (int j2 = 0; j2 < 32; ++j2) acc += hl[j2]*s_w[j2*32+o];
    float f = fmaxf(acc, 0.f);
    pa0 += f*s_wc[(2+o)*2];  pa1 += f*s_wc[(2+o)*2+1];
    pb0 += f*s_wc[(34+o)*2]; pb1 += f*s_wc[(34+o)*2+1];
  }
  pa0 += __shfl_xor(pa0,1); pa0 += __shfl_xor(pa0,2);
  pa1 += __shfl_xor(pa1,1); pa1 += __shfl_xor(pa1,2);
  pb0 += __shfl_xor(pb0,1); pb0 += __shfl_xor(pb0,2);
  pb1 += __shfl_xor(pb1,1); pb1 += __shfl_xor(pb1,2);
  if (valid){
    if (head == 0)      ((float2*)asrc)[i] = make_float2(pa0, pa1);
    else if (head == 1) ((float2*)bdst)[i] = make_float2(pb0, pb1);
  }
}

// out[e] = ef[e]@Wc[0:2] + asrc[src] + bdst[dst] + bc  (float2 store)
__global__ void k_edge_final(const int* __restrict__ ei, const float* __restrict__ ew,
                             const float* __restrict__ ce, const float* __restrict__ asrc,
                             const float* __restrict__ bdst, const float* __restrict__ wc,
                             const float* __restrict__ bc, float2* __restrict__ out, int E){
  int e = blockIdx.x*blockDim.x + threadIdx.x;
  if (e >= E) return;
  int s = ei[e], d = ei[E+e];
  float f0 = ew[e], f1 = ce[e];
  float2 a = ((const float2*)asrc)[s];
  float2 b = ((const float2*)bdst)[d];
  out[e] = make_float2(f0*wc[0] + f1*wc[2] + a.x + b.x + bc[0],
                       f0*wc[1] + f1*wc[3] + a.y + b.y + bc[1]);
}

extern "C" void kernel_launch(void* const* d_in, const int* in_sizes, int n_in,
                              void* d_out, int out_size, void* d_ws, size_t ws_size,
                              hipStream_t stream){
  const float* x     = (const float*)d_in[0];
  const int*   ei    = (const int*)  d_in[1];
  const float* ew    = (const float*)d_in[2];
  const float* ce    = (const float*)d_in[3];
  const float* w_init= (const float*)d_in[4];
  const float* b_init= (const float*)d_in[5];
  const float* w1l   = (const float*)d_in[6];
  const float* b1l   = (const float*)d_in[7];
  const float* w1r   = (const float*)d_in[8];
  const float* b1r   = (const float*)d_in[9];
  const float* w1e   = (const float*)d_in[10];
  const float* att1  = (const float*)d_in[11];
  const float* bias1 = (const float*)d_in[12];
  const float* w2l   = (const float*)d_in[13];
  const float* b2l   = (const float*)d_in[14];
  const float* w2r   = (const float*)d_in[15];
  const float* b2r   = (const float*)d_in[16];
  const float* w2e   = (const float*)d_in[17];
  const float* att2  = (const float*)d_in[18];
  const float* bias2 = (const float*)d_in[19];
  const float* w_fc  = (const float*)d_in[20];
  const float* b_fc  = (const float*)d_in[21];
  const float* w_e1  = (const float*)d_in[22];
  const float* b_e1  = (const float*)d_in[23];
  const float* w_e2  = (const float*)d_in[24];
  const float* b_e2  = (const float*)d_in[25];

  const int n = in_sizes[0]/5;     // 100000
  const int E = in_sizes[2];       // 3200000
  const int ntiles = (E + TTILE - 1) / TTILE;     // ~196
  const int nbk    = (n + BKN - 1) >> BSH;        // ~782 buckets (<=1024)
  const int M      = nbk * ntiles;                // hist matrix size
  const int nbA    = (M + 255) >> 8;              // hmat-scan blocks (<=1024)

  // ---- workspace layout: 128B-aligned (32 x 4B units) ----
  int*   W32 = (int*)d_ws;
  float* Wf  = (float*)d_ws;
  size_t off = 0;
  auto nxt = [&off](size_t cnt){ size_t p = off; off += (cnt + 31) & ~(size_t)31; return p; };
  int*   rowstart = W32 + nxt((size_t)n + 1);
  int*   bsum     = W32 + nxt(nbA);
  int*   boffs    = W32 + nxt(nbA);
  int*   hmat     = W32 + nxt(M);
  int*   gofs     = W32 + nxt(M);
  float* wc       = Wf  + nxt(160);
  float* bc       = wc + 132;
  int4*  csr      = (int4*)(W32 + nxt((size_t)4*E));
  // big region: tmp (4E ints, dead after k_bucket) aliased with node scratch.
  size_t na = ((size_t)n + 31) & ~(size_t)31;
  size_t bigsz = (size_t)4*E > 80*na ? (size_t)4*E : 80*na;
  float* S    = Wf + nxt(bigsz);
  int4*  tmp  = (int4*)S;
  float* xl1  = S;              // 16n, dead after agg1
  float* xr1  = S + 16*na;      // 16n, dead after agg1
  float* h1   = S + 32*na;      // 16n, dead after pre2
  float* xl2  = S;              // 32n (over xl1/xr1)
  float* xr2  = S + 48*na;      // 32n
  float* asrc = S + 32*na;      // 2n  (over h1, dead)
  float* bdst = S + 34*na;      // 2n

  dim3 blk(256);
  dim3 ge((E + 255)/256), gn((n + 255)/256), gn4(((size_t)4*n + 255)/256);

  k_wcomb<<<1,192,0,stream>>>(w_e1,b_e1,w_e2,b_e2,wc,bc);

  // ---- CSR build: LDS counting sort (zero global atomics) ----
  k_histT<<<ntiles,256,0,stream>>>(ei + E, hmat, E, ntiles, nbk);
  k_scan1<<<nbA,256,0,stream>>>(hmat,bsum,M);
  k_scan2<<<1,1024,0,stream>>>(bsum,boffs,nbA);
  k_scan3g<<<nbA,256,0,stream>>>(hmat,boffs,gofs,M);
  k_partition<<<ntiles,256,0,stream>>>(ei,ew,ce,gofs,tmp,E,ntiles,nbk);
  k_bucket<<<nbk,256,0,stream>>>(tmp,gofs,rowstart,csr,n,E,ntiles,nbk);

  // ---- GATv2 layer 1 (in 8, C=4) ----
  k_pre1<<<gn,blk,0,stream>>>(x,w_init,b_init,w1l,b1l,w1r,b1r,xl1,xr1,n);
  k_agg1<<<gn4,blk,0,stream>>>(rowstart,csr,xl1,xr1,w1e,att1,bias1,h1,n);

  // ---- GATv2 layer 2 (in 16, C=8) + fused fc/edge-MLP node terms ----
  k_pre2<<<gn,blk,0,stream>>>(h1,w2l,b2l,w2r,b2r,xl2,xr2,n);
  k_agg2f<<<gn4,blk,0,stream>>>(rowstart,csr,xl2,xr2,w2e,att2,bias2,w_fc,b_fc,wc,asrc,bdst,n);

  // ---- edge scores ----
  k_edge_final<<<ge,blk,0,stream>>>(ei,ew,ce,asrc,bdst,wc,bc,(float2*)d_out,E);
}

// Round 9
// 512.674 us; speedup vs baseline: 2.6420x; 1.1103x over previous
//
#include <hip/hip_runtime.h>

// KEPCE_GAT r9: split-K aggregation — 8 threads/node (4 heads x 2 edge-halves),
// online-softmax states merged via shfl_xor(4). CSR build unchanged from r8
// (LDS counting sort, zero global atomics).

__device__ __forceinline__ float lrelu(float v){ return v > 0.f ? v : 0.2f*v; }

#define BSH   7        // bucket = dst >> 7  (128 dsts/bucket)
#define BKN   (1<<BSH)
#define TTILE 16384    // edges per partition tile (256 thr x 64)

// Fold edge MLP: Wc[66,2] = w_e1[66,32] @ w_e2[32,2]; bc[2] = b_e1@w_e2 + b_e2.
__global__ void k_wcomb(const float* __restrict__ we1, const float* __restrict__ be1,
                        const float* __restrict__ we2, const float* __restrict__ be2,
                        float* __restrict__ wc, float* __restrict__ bc){
  int t = threadIdx.x;
  if (t < 132){
    int i = t >> 1, k = t & 1;
    float acc = 0.f;
    for (int j = 0; j < 32; ++j) acc += we1[i*32+j]*we2[j*2+k];
    wc[t] = acc;
  } else if (t < 134){
    int k = t - 132;
    float acc = be2[k];
    for (int j = 0; j < 32; ++j) acc += be1[j]*we2[j*2+k];
    bc[k] = acc;
  }
}

// Scan stage 1: per-256-block sums.
__global__ void k_scan1(const int* __restrict__ src, int* __restrict__ bsum, int n){
  __shared__ int lds[256];
  int t = threadIdx.x, k = blockIdx.x*256 + t;
  lds[t] = (k < n) ? src[k] : 0;
  __syncthreads();
  #pragma unroll
  for (int off = 1; off < 256; off <<= 1){
    int u = (t >= off) ? lds[t-off] : 0;
    __syncthreads();
    lds[t] += u;
    __syncthreads();
  }
  if (t == 255) bsum[blockIdx.x] = lds[255];
}

// Scan stage 2: exclusive scan of block sums (nb <= 1024). One block.
__global__ void k_scan2(const int* __restrict__ bsum, int* __restrict__ boffs, int nb){
  __shared__ int lds[1024];
  int t = threadIdx.x;
  int v = (t < nb) ? bsum[t] : 0;
  lds[t] = v;
  __syncthreads();
  #pragma unroll
  for (int off = 1; off < 1024; off <<= 1){
    int u = (t >= off) ? lds[t-off] : 0;
    __syncthreads();
    lds[t] += u;
    __syncthreads();
  }
  if (t < nb) boffs[t] = lds[t] - v;
}

// Scan stage 3: exclusive scan into out.
__global__ void k_scan3g(const int* __restrict__ src, const int* __restrict__ boffs,
                         int* __restrict__ out, int n){
  __shared__ int lds[256];
  int t = threadIdx.x, k = blockIdx.x*256 + t;
  int v = (k < n) ? src[k] : 0;
  lds[t] = v;
  __syncthreads();
  #pragma unroll
  for (int off = 1; off < 256; off <<= 1){
    int u = (t >= off) ? lds[t-off] : 0;
    __syncthreads();
    lds[t] += u;
    __syncthreads();
  }
  if (k < n) out[k] = boffs[blockIdx.x] + lds[t] - v;
}

// Per-tile bucket histogram (LDS) -> hmat[bucket][tile] (bucket-major).
__global__ void k_histT(const int* __restrict__ dst, int* __restrict__ hmat,
                        int E, int ntiles, int nbk){
  __shared__ int cnt[1024];
  int tile = blockIdx.x, lt = threadIdx.x;
  for (int b = lt; b < nbk; b += 256) cnt[b] = 0;
  __syncthreads();
  int tb = tile*TTILE;
  #pragma unroll 4
  for (int r = 0; r < TTILE/256; ++r){
    int e = tb + r*256 + lt;
    if (e < E) atomicAdd(&cnt[dst[e] >> BSH], 1);
  }
  __syncthreads();
  for (int b = lt; b < nbk; b += 256) hmat[(size_t)b*ntiles + tile] = cnt[b];
}

// Partition pass: streaming re-read of edge arrays; LDS ranks; write int4
// records {src,w,c,dst} to exact (bucket,tile) offsets -> bucket-grouped tmp.
__global__ void k_partition(const int* __restrict__ ei, const float* __restrict__ ew,
                            const float* __restrict__ ce, const int* __restrict__ gofs,
                            int4* __restrict__ tmp, int E, int ntiles, int nbk){
  __shared__ int cnt[1024];
  __shared__ int base[1024];
  int tile = blockIdx.x, lt = threadIdx.x;
  for (int b = lt; b < nbk; b += 256){
    cnt[b] = 0;
    base[b] = gofs[(size_t)b*ntiles + tile];
  }
  __syncthreads();
  int tb = tile*TTILE;
  #pragma unroll 4
  for (int r = 0; r < TTILE/256; ++r){
    int e = tb + r*256 + lt;
    if (e < E){
      int d = ei[E+e];
      int bk = d >> BSH;
      int rk = atomicAdd(&cnt[bk], 1);
      tmp[base[bk] + rk] = make_int4(ei[e], __float_as_int(ew[e]),
                                     __float_as_int(ce[e]), d);
    }
  }
}

// Per-bucket finalize: LDS dst-histogram -> scan -> rowstart + exact placement.
__global__ void k_bucket(const int4* __restrict__ tmp, const int* __restrict__ gofs,
                         int* __restrict__ rowstart, int4* __restrict__ csr,
                         int n, int E, int ntiles, int nbk){
  __shared__ int cnt[BKN];
  __shared__ int sc[BKN];
  __shared__ int cur[BKN];
  int b = blockIdx.x, lt = threadIdx.x;
  int d0 = b << BSH;
  int segs = gofs[(size_t)b*ntiles];
  int sege = (b+1 < nbk) ? gofs[(size_t)(b+1)*ntiles] : E;
  if (lt < BKN) cnt[lt] = 0;
  __syncthreads();
  for (int j = segs + lt; j < sege; j += 256)
    atomicAdd(&cnt[tmp[j].w & (BKN-1)], 1);
  __syncthreads();
  if (lt < BKN) sc[lt] = cnt[lt];
  __syncthreads();
  #pragma unroll
  for (int off = 1; off < BKN; off <<= 1){
    int u = (lt >= off && lt < BKN) ? sc[lt-off] : 0;
    __syncthreads();
    if (lt < BKN) sc[lt] += u;
    __syncthreads();
  }
  if (lt < BKN){
    int excl = segs + sc[lt] - cnt[lt];
    cur[lt] = excl;
    int d = d0 + lt;
    if (d < n) rowstart[d] = excl;
  }
  if (b == 0 && lt == 0) rowstart[n] = E;
  __syncthreads();
  for (int j = segs + lt; j < sege; j += 256){
    int4 rec = tmp[j];
    int pos = atomicAdd(&cur[rec.w & (BKN-1)], 1);
    csr[pos] = rec;
  }
}

// Fused init+pre layer1: h0 = relu(x@wi+bi) in regs; xl1/xr1 = h0@Wl/Wr + b.
__global__ void k_pre1(const float* __restrict__ x, const float* __restrict__ wi,
                       const float* __restrict__ bi, const float* __restrict__ wl,
                       const float* __restrict__ bl, const float* __restrict__ wr,
                       const float* __restrict__ br, float* __restrict__ xl,
                       float* __restrict__ xr, int n){
  int i = blockIdx.x*blockDim.x + threadIdx.x;
  if (i >= n) return;
  float xi[5];
  #pragma unroll
  for (int j = 0; j < 5; ++j) xi[j] = x[i*5+j];
  float h[8];
  #pragma unroll
  for (int o = 0; o < 8; ++o){
    float acc = bi[o];
    #pragma unroll
    for (int j = 0; j < 5; ++j) acc += xi[j]*wi[j*8+o];
    h[o] = fmaxf(acc, 0.f);
  }
  #pragma unroll
  for (int o = 0; o < 16; ++o){
    float a = bl[o], r = br[o];
    #pragma unroll
    for (int j = 0; j < 8; ++j){ a += h[j]*wl[j*16+o]; r += h[j]*wr[j*16+o]; }
    xl[(size_t)i*16+o] = a;
    xr[(size_t)i*16+o] = r;
  }
}

// xl = hin@Wl+bl, xr = hin@Wr+br (layer2: 16 -> 32).
__global__ void k_pre2(const float* __restrict__ hin,
                       const float* __restrict__ wl, const float* __restrict__ bl,
                       const float* __restrict__ wr, const float* __restrict__ br,
                       float* __restrict__ xl, float* __restrict__ xr, int n){
  int i = blockIdx.x*blockDim.x + threadIdx.x;
  if (i >= n) return;
  float h[16];
  #pragma unroll
  for (int j = 0; j < 16; ++j) h[j] = hin[(size_t)i*16+j];
  #pragma unroll
  for (int o = 0; o < 32; ++o){
    float a = bl[o], r = br[o];
    #pragma unroll
    for (int j = 0; j < 16; ++j){ a += h[j]*wl[j*32+o]; r += h[j]*wr[j*32+o]; }
    xl[(size_t)i*32+o] = a;
    xr[(size_t)i*32+o] = r;
  }
}

// Layer-1 aggregation, split-K: 8 threads/node = (head, edge-half).
// Online softmax per half; merge via shfl_xor(4); self-loop applied last.
__global__ void k_agg1(const int* __restrict__ rowstart, const int4* __restrict__ csr,
                       const float* __restrict__ xl, const float* __restrict__ xr,
                       const float* __restrict__ we, const float* __restrict__ att,
                       const float* __restrict__ bias, float* __restrict__ hout, int n){
  constexpr int C = 4, HC = 16;
  int t = blockIdx.x*blockDim.x + threadIdx.x;
  int i = t >> 3, l = t & 7, head = l & 3, half = l >> 2;
  if (i >= n) return;
  float weA[C], weB[C], AT[C], BS[C];
  #pragma unroll
  for (int c = 0; c < C; ++c){
    int o = head*C + c;
    weA[c] = we[o]; weB[c] = we[HC+o]; AT[c] = att[o]; BS[c] = bias[o];
  }
  float XR[C];
  {
    float4 b = *(const float4*)(xr + (size_t)i*HC + head*C);
    XR[0]=b.x; XR[1]=b.y; XR[2]=b.z; XR[3]=b.w;
  }
  float m = -3.0e38f, den = 0.f, sw = 0.f, sc = 0.f;
  float num[C] = {0.f,0.f,0.f,0.f};
  int rs = rowstart[i], re = rowstart[i+1];
  int mid = rs + ((re - rs) >> 1);
  int jb = half ? mid : rs, je = half ? re : mid;
  int j = jb;
  for (; j + 2 <= je; j += 2){
    int4 pa = csr[j], pb = csr[j+1];
    float4 qa = *(const float4*)(xl + (size_t)pa.x*HC + head*C);
    float4 qb = *(const float4*)(xl + (size_t)pb.x*HC + head*C);
    float f0a = __int_as_float(pa.y), f1a = __int_as_float(pa.z);
    float f0b = __int_as_float(pb.y), f1b = __int_as_float(pb.z);
    sw += f0a + f0b; sc += f1a + f1b;
    float XA[C] = {qa.x,qa.y,qa.z,qa.w};
    float XB[C] = {qb.x,qb.y,qb.z,qb.w};
    float aa = 0.f, ab = 0.f;
    #pragma unroll
    for (int c = 0; c < C; ++c) aa += AT[c]*lrelu(XA[c] + XR[c] + f0a*weA[c] + f1a*weB[c]);
    #pragma unroll
    for (int c = 0; c < C; ++c) ab += AT[c]*lrelu(XB[c] + XR[c] + f0b*weA[c] + f1b*weB[c]);
    float nm = fmaxf(m, aa);
    float r = __expf(m - nm), ex = __expf(aa - nm);
    den = den*r + ex;
    #pragma unroll
    for (int c = 0; c < C; ++c) num[c] = num[c]*r + ex*XA[c];
    m = nm;
    nm = fmaxf(m, ab); r = __expf(m - nm); ex = __expf(ab - nm);
    den = den*r + ex;
    #pragma unroll
    for (int c = 0; c < C; ++c) num[c] = num[c]*r + ex*XB[c];
    m = nm;
  }
  if (j < je){
    int4 pa = csr[j];
    float4 qa = *(const float4*)(xl + (size_t)pa.x*HC + head*C);
    float f0a = __int_as_float(pa.y), f1a = __int_as_float(pa.z);
    sw += f0a; sc += f1a;
    float XA[C] = {qa.x,qa.y,qa.z,qa.w};
    float aa = 0.f;
    #pragma unroll
    for (int c = 0; c < C; ++c) aa += AT[c]*lrelu(XA[c] + XR[c] + f0a*weA[c] + f1a*weB[c]);
    float nm = fmaxf(m, aa);
    float r = __expf(m - nm), ex = __expf(aa - nm);
    den = den*r + ex;
    #pragma unroll
    for (int c = 0; c < C; ++c) num[c] = num[c]*r + ex*XA[c];
    m = nm;
  }
  // merge halves (shfl_xor 4 stays within the node's 8-lane group)
  {
    float mo  = __shfl_xor(m, 4);
    float dno = __shfl_xor(den, 4);
    float swo = __shfl_xor(sw, 4), sco = __shfl_xor(sc, 4);
    float nm = fmaxf(m, mo);
    float r0 = __expf(m - nm), r1 = __expf(mo - nm);
    den = den*r0 + dno*r1;
    #pragma unroll
    for (int c = 0; c < C; ++c){
      float no = __shfl_xor(num[c], 4);
      num[c] = num[c]*r0 + no*r1;
    }
    m = nm; sw += swo; sc += sco;
  }
  // self-loop last (mean edge attrs from merged sums)
  float cf = fmaxf((float)(re - rs), 1.f);
  float la0 = sw/cf, la1 = sc/cf;
  float4 qs = *(const float4*)(xl + (size_t)i*HC + head*C);
  float XS[C] = {qs.x,qs.y,qs.z,qs.w};
  float as = 0.f;
  #pragma unroll
  for (int c = 0; c < C; ++c) as += AT[c]*lrelu(XS[c] + XR[c] + la0*weA[c] + la1*weB[c]);
  float nm = fmaxf(m, as);
  float r = __expf(m - nm), ex = __expf(as - nm);
  den = den*r + ex;
  #pragma unroll
  for (int c = 0; c < C; ++c) num[c] = num[c]*r + ex*XS[c];
  if (half == 0){
    float inv = 1.f/den;
    #pragma unroll
    for (int c = 0; c < C; ++c)
      hout[(size_t)i*HC + head*C + c] = fmaxf(num[c]*inv + BS[c], 0.f);
  }
}

// Layer-2 aggregation, split-K (8 thr/node) + fused fc/edge-MLP epilogue.
__global__ void k_agg2f(const int* __restrict__ rowstart, const int4* __restrict__ csr,
                        const float* __restrict__ xl, const float* __restrict__ xr,
                        const float* __restrict__ we, const float* __restrict__ att,
                        const float* __restrict__ bias, const float* __restrict__ wfc,
                        const float* __restrict__ bfc, const float* __restrict__ wc,
                        float* __restrict__ asrc, float* __restrict__ bdst, int n){
  constexpr int C = 8, HC = 32;
  __shared__ float s_h[32*33];
  __shared__ float s_w[1024];
  __shared__ float s_wc[134];
  int lt = threadIdx.x;
  for (int k = lt; k < 1024; k += 256) s_w[k] = wfc[k];
  if (lt < 134) s_wc[lt] = wc[lt];
  int t = blockIdx.x*blockDim.x + lt;
  int i = t >> 3, l = lt & 7, head = l & 3, half = l >> 2;
  bool valid = i < n;
  int ic = valid ? i : 0;
  float weA[C], weB[C], AT[C], BS[C];
  #pragma unroll
  for (int c = 0; c < C; ++c){
    int o = head*C + c;
    weA[c] = we[o]; weB[c] = we[HC+o]; AT[c] = att[o]; BS[c] = bias[o];
  }
  float XR[C];
  {
    const float4* pr = (const float4*)(xr + (size_t)ic*HC + head*C);
    float4 b0 = pr[0], b1 = pr[1];
    XR[0]=b0.x; XR[1]=b0.y; XR[2]=b0.z; XR[3]=b0.w;
    XR[4]=b1.x; XR[5]=b1.y; XR[6]=b1.z; XR[7]=b1.w;
  }
  float m = -3.0e38f, den = 0.f, sw = 0.f, sc = 0.f;
  float num[C] = {0.f,0.f,0.f,0.f,0.f,0.f,0.f,0.f};
  int rs = 0, re = 0;
  if (valid){ rs = rowstart[i]; re = rowstart[i+1]; }
  int mid = rs + ((re - rs) >> 1);
  int jb = half ? mid : rs, je = half ? re : mid;
  int j = jb;
  for (; j + 2 <= je; j += 2){
    int4 pa = csr[j], pb = csr[j+1];
    const float4* qa = (const float4*)(xl + (size_t)pa.x*HC + head*C);
    const float4* qb = (const float4*)(xl + (size_t)pb.x*HC + head*C);
    float4 a0 = qa[0], a1 = qa[1], b0 = qb[0], b1 = qb[1];
    float f0a = __int_as_float(pa.y), f1a = __int_as_float(pa.z);
    float f0b = __int_as_float(pb.y), f1b = __int_as_float(pb.z);
    sw += f0a + f0b; sc += f1a + f1b;
    float XA[C] = {a0.x,a0.y,a0.z,a0.w,a1.x,a1.y,a1.z,a1.w};
    float XB[C] = {b0.x,b0.y,b0.z,b0.w,b1.x,b1.y,b1.z,b1.w};
    float aa = 0.f, ab = 0.f;
    #pragma unroll
    for (int c = 0; c < C; ++c) aa += AT[c]*lrelu(XA[c] + XR[c] + f0a*weA[c] + f1a*weB[c]);
    #pragma unroll
    for (int c = 0; c < C; ++c) ab += AT[c]*lrelu(XB[c] + XR[c] + f0b*weA[c] + f1b*weB[c]);
    float nm = fmaxf(m, aa);
    float r = __expf(m - nm), ex = __expf(aa - nm);
    den = den*r + ex;
    #pragma unroll
    for (int c = 0; c < C; ++c) num[c] = num[c]*r + ex*XA[c];
    m = nm;
    nm = fmaxf(m, ab); r = __expf(m - nm); ex = __expf(ab - nm);
    den = den*r + ex;
    #pragma unroll
    for (int c = 0; c < C; ++c) num[c] = num[c]*r + ex*XB[c];
    m = nm;
  }
  if (j < je){
    int4 pa = csr[j];
    const float4* qa = (const float4*)(xl + (size_t)pa.x*HC + head*C);
    float4 a0 = qa[0], a1 = qa[1];
    float f0a = __int_as_float(pa.y), f1a = __int_as_float(pa.z);
    sw += f0a; sc += f1a;
    float XA[C] = {a0.x,a0.y,a0.z,a0.w,a1.x,a1.y,a1.z,a1.w};
    float aa = 0.f;
    #pragma unroll
    for (int c = 0; c < C; ++c) aa += AT[c]*lrelu(XA[c] + XR[c] + f0a*weA[c] + f1a*weB[c]);
    float nm = fmaxf(m, aa);
    float r = __expf(m - nm), ex = __expf(aa - nm);
    den = den*r + ex;
    #pragma unroll
    for (int c = 0; c < C; ++c) num[c] = num[c]*r + ex*XA[c];
    m = nm;
  }
  // merge halves
  {
    float mo  = __shfl_xor(m, 4);
    float dno = __shfl_xor(den, 4);
    float swo = __shfl_xor(sw, 4), sco = __shfl_xor(sc, 4);
    float nm = fmaxf(m, mo);
    float r0 = __expf(m - nm), r1 = __expf(mo - nm);
    den = den*r0 + dno*r1;
    #pragma unroll
    for (int c = 0; c < C; ++c){
      float no = __shfl_xor(num[c], 4);
      num[c] = num[c]*r0 + no*r1;
    }
    m = nm; sw += swo; sc += sco;
  }
  // self-loop + output slice
  if (valid){
    float cf = fmaxf((float)(re - rs), 1.f);
    float la0 = sw/cf, la1 = sc/cf;
    const float4* pl = (const float4*)(xl + (size_t)i*HC + head*C);
    float4 s0 = pl[0], s1 = pl[1];
    float XS[C] = {s0.x,s0.y,s0.z,s0.w,s1.x,s1.y,s1.z,s1.w};
    float as = 0.f;
    #pragma unroll
    for (int c = 0; c < C; ++c) as += AT[c]*lrelu(XS[c] + XR[c] + la0*weA[c] + la1*weB[c]);
    float nm = fmaxf(m, as);
    float r = __expf(m - nm), ex = __expf(as - nm);
    den = den*r + ex;
    #pragma unroll
    for (int c = 0; c < C; ++c) num[c] = num[c]*r + ex*XS[c];
  }
  int ln = lt >> 3;
  if (half == 0){
    float inv = valid ? 1.f/den : 0.f;
    #pragma unroll
    for (int c = 0; c < C; ++c)
      s_h[ln*33 + head*C + c] = valid ? fmaxf(num[c]*inv + BS[c], 0.f) : 0.f;
  }
  __syncthreads();
  float hl[32];
  #pragma unroll
  for (int j2 = 0; j2 < 32; ++j2) hl[j2] = s_h[ln*33 + j2];
  float pa0=0.f, pa1=0.f, pb0=0.f, pb1=0.f;
  #pragma unroll
  for (int k = 0; k < 4; ++k){
    int o = l*4 + k;
    float acc = bfc[o];
    #pragma unroll
    for (int j2 = 0; j2 < 32; ++j2) acc += hl[j2]*s_w[j2*32+o];
    float f = fmaxf(acc, 0.f);
    pa0 += f*s_wc[(2+o)*2];  pa1 += f*s_wc[(2+o)*2+1];
    pb0 += f*s_wc[(34+o)*2]; pb1 += f*s_wc[(34+o)*2+1];
  }
  pa0 += __shfl_xor(pa0,1); pa0 += __shfl_xor(pa0,2); pa0 += __shfl_xor(pa0,4);
  pa1 += __shfl_xor(pa1,1); pa1 += __shfl_xor(pa1,2); pa1 += __shfl_xor(pa1,4);
  pb0 += __shfl_xor(pb0,1); pb0 += __shfl_xor(pb0,2); pb0 += __shfl_xor(pb0,4);
  pb1 += __shfl_xor(pb1,1); pb1 += __shfl_xor(pb1,2); pb1 += __shfl_xor(pb1,4);
  if (valid){
    if (l == 0)      ((float2*)asrc)[i] = make_float2(pa0, pa1);
    else if (l == 1) ((float2*)bdst)[i] = make_float2(pb0, pb1);
  }
}

// out[e] = ef[e]@Wc[0:2] + asrc[src] + bdst[dst] + bc  (float2 store)
__global__ void k_edge_final(const int* __restrict__ ei, const float* __restrict__ ew,
                             const float* __restrict__ ce, const float* __restrict__ asrc,
                             const float* __restrict__ bdst, const float* __restrict__ wc,
                             const float* __restrict__ bc, float2* __restrict__ out, int E){
  int e = blockIdx.x*blockDim.x + threadIdx.x;
  if (e >= E) return;
  int s = ei[e], d = ei[E+e];
  float f0 = ew[e], f1 = ce[e];
  float2 a = ((const float2*)asrc)[s];
  float2 b = ((const float2*)bdst)[d];
  out[e] = make_float2(f0*wc[0] + f1*wc[2] + a.x + b.x + bc[0],
                       f0*wc[1] + f1*wc[3] + a.y + b.y + bc[1]);
}

extern "C" void kernel_launch(void* const* d_in, const int* in_sizes, int n_in,
                              void* d_out, int out_size, void* d_ws, size_t ws_size,
                              hipStream_t stream){
  const float* x     = (const float*)d_in[0];
  const int*   ei    = (const int*)  d_in[1];
  const float* ew    = (const float*)d_in[2];
  const float* ce    = (const float*)d_in[3];
  const float* w_init= (const float*)d_in[4];
  const float* b_init= (const float*)d_in[5];
  const float* w1l   = (const float*)d_in[6];
  const float* b1l   = (const float*)d_in[7];
  const float* w1r   = (const float*)d_in[8];
  const float* b1r   = (const float*)d_in[9];
  const float* w1e   = (const float*)d_in[10];
  const float* att1  = (const float*)d_in[11];
  const float* bias1 = (const float*)d_in[12];
  const float* w2l   = (const float*)d_in[13];
  const float* b2l   = (const float*)d_in[14];
  const float* w2r   = (const float*)d_in[15];
  const float* b2r   = (const float*)d_in[16];
  const float* w2e   = (const float*)d_in[17];
  const float* att2  = (const float*)d_in[18];
  const float* bias2 = (const float*)d_in[19];
  const float* w_fc  = (const float*)d_in[20];
  const float* b_fc  = (const float*)d_in[21];
  const float* w_e1  = (const float*)d_in[22];
  const float* b_e1  = (const float*)d_in[23];
  const float* w_e2  = (const float*)d_in[24];
  const float* b_e2  = (const float*)d_in[25];

  const int n = in_sizes[0]/5;     // 100000
  const int E = in_sizes[2];       // 3200000
  const int ntiles = (E + TTILE - 1) / TTILE;     // ~196
  const int nbk    = (n + BKN - 1) >> BSH;        // ~782 buckets (<=1024)
  const int M      = nbk * ntiles;
  const int nbA    = (M + 255) >> 8;              // hmat-scan blocks (<=1024)

  // ---- workspace layout: 128B-aligned (32 x 4B units) ----
  int*   W32 = (int*)d_ws;
  float* Wf  = (float*)d_ws;
  size_t off = 0;
  auto nxt = [&off](size_t cnt){ size_t p = off; off += (cnt + 31) & ~(size_t)31; return p; };
  int*   rowstart = W32 + nxt((size_t)n + 1);
  int*   bsum     = W32 + nxt(nbA);
  int*   boffs    = W32 + nxt(nbA);
  int*   hmat     = W32 + nxt(M);
  int*   gofs     = W32 + nxt(M);
  float* wc       = Wf  + nxt(160);
  float* bc       = wc + 132;
  int4*  csr      = (int4*)(W32 + nxt((size_t)4*E));
  size_t na = ((size_t)n + 31) & ~(size_t)31;
  size_t bigsz = (size_t)4*E > 80*na ? (size_t)4*E : 80*na;
  float* S    = Wf + nxt(bigsz);
  int4*  tmp  = (int4*)S;
  float* xl1  = S;              // 16n, dead after agg1
  float* xr1  = S + 16*na;      // 16n, dead after agg1
  float* h1   = S + 32*na;      // 16n, dead after pre2
  float* xl2  = S;              // 32n (over xl1/xr1)
  float* xr2  = S + 48*na;      // 32n
  float* asrc = S + 32*na;      // 2n  (over h1, dead)
  float* bdst = S + 34*na;      // 2n

  dim3 blk(256);
  dim3 ge((E + 255)/256), gn((n + 255)/256), gn8(((size_t)8*n + 255)/256);

  k_wcomb<<<1,192,0,stream>>>(w_e1,b_e1,w_e2,b_e2,wc,bc);

  // ---- CSR build: LDS counting sort (zero global atomics) ----
  k_histT<<<ntiles,256,0,stream>>>(ei + E, hmat, E, ntiles, nbk);
  k_scan1<<<nbA,256,0,stream>>>(hmat,bsum,M);
  k_scan2<<<1,1024,0,stream>>>(bsum,boffs,nbA);
  k_scan3g<<<nbA,256,0,stream>>>(hmat,boffs,gofs,M);
  k_partition<<<ntiles,256,0,stream>>>(ei,ew,ce,gofs,tmp,E,ntiles,nbk);
  k_bucket<<<nbk,256,0,stream>>>(tmp,gofs,rowstart,csr,n,E,ntiles,nbk);

  // ---- GATv2 layer 1 (in 8, C=4) ----
  k_pre1<<<gn,blk,0,stream>>>(x,w_init,b_init,w1l,b1l,w1r,b1r,xl1,xr1,n);
  k_agg1<<<gn8,blk,0,stream>>>(rowstart,csr,xl1,xr1,w1e,att1,bias1,h1,n);

  // ---- GATv2 layer 2 (in 16, C=8) + fused fc/edge-MLP node terms ----
  k_pre2<<<gn,blk,0,stream>>>(h1,w2l,b2l,w2r,b2r,xl2,xr2,n);
  k_agg2f<<<gn8,blk,0,stream>>>(rowstart,csr,xl2,xr2,w2e,att2,bias2,w_fc,b_fc,wc,asrc,bdst,n);

  // ---- edge scores ----
  k_edge_final<<<ge,blk,0,stream>>>(ei,ew,ce,asrc,bdst,wc,bc,(float2*)d_out,E);
}

// Round 10
// 493.260 us; speedup vs baseline: 2.7460x; 1.0394x over previous
//
#include <hip/hip_runtime.h>

// KEPCE_GAT r10: r9 + TTILE 16384->4096 (782 partition/hist blocks, 4x shorter
// serial chains) + 3-level hierarchical scan for the 611K-entry hist matrix.
// Agg: split-K 8 thr/node online softmax; CSR build: LDS counting sort,
// zero global atomics.

__device__ __forceinline__ float lrelu(float v){ return v > 0.f ? v : 0.2f*v; }

#define BSH   7        // bucket = dst >> 7  (128 dsts/bucket)
#define BKN   (1<<BSH)
#define TTILE 4096     // edges per partition tile (256 thr x 16)

// Fold edge MLP: Wc[66,2] = w_e1[66,32] @ w_e2[32,2]; bc[2] = b_e1@w_e2 + b_e2.
__global__ void k_wcomb(const float* __restrict__ we1, const float* __restrict__ be1,
                        const float* __restrict__ we2, const float* __restrict__ be2,
                        float* __restrict__ wc, float* __restrict__ bc){
  int t = threadIdx.x;
  if (t < 132){
    int i = t >> 1, k = t & 1;
    float acc = 0.f;
    for (int j = 0; j < 32; ++j) acc += we1[i*32+j]*we2[j*2+k];
    wc[t] = acc;
  } else if (t < 134){
    int k = t - 132;
    float acc = be2[k];
    for (int j = 0; j < 32; ++j) acc += be1[j]*we2[j*2+k];
    bc[k] = acc;
  }
}

// Scan stage 1: per-256-block sums.
__global__ void k_scan1(const int* __restrict__ src, int* __restrict__ bsum, int n){
  __shared__ int lds[256];
  int t = threadIdx.x, k = blockIdx.x*256 + t;
  lds[t] = (k < n) ? src[k] : 0;
  __syncthreads();
  #pragma unroll
  for (int off = 1; off < 256; off <<= 1){
    int u = (t >= off) ? lds[t-off] : 0;
    __syncthreads();
    lds[t] += u;
    __syncthreads();
  }
  if (t == 255) bsum[blockIdx.x] = lds[255];
}

// Scan stage 2: exclusive scan (nb <= 1024). One block.
__global__ void k_scan2(const int* __restrict__ bsum, int* __restrict__ boffs, int nb){
  __shared__ int lds[1024];
  int t = threadIdx.x;
  int v = (t < nb) ? bsum[t] : 0;
  lds[t] = v;
  __syncthreads();
  #pragma unroll
  for (int off = 1; off < 1024; off <<= 1){
    int u = (t >= off) ? lds[t-off] : 0;
    __syncthreads();
    lds[t] += u;
    __syncthreads();
  }
  if (t < nb) boffs[t] = lds[t] - v;
}

// Scan stage 3: exclusive scan into out, adding per-block offsets.
__global__ void k_scan3g(const int* __restrict__ src, const int* __restrict__ boffs,
                         int* __restrict__ out, int n){
  __shared__ int lds[256];
  int t = threadIdx.x, k = blockIdx.x*256 + t;
  int v = (k < n) ? src[k] : 0;
  lds[t] = v;
  __syncthreads();
  #pragma unroll
  for (int off = 1; off < 256; off <<= 1){
    int u = (t >= off) ? lds[t-off] : 0;
    __syncthreads();
    lds[t] += u;
    __syncthreads();
  }
  if (k < n) out[k] = boffs[blockIdx.x] + lds[t] - v;
}

// Per-tile bucket histogram (LDS) -> hmat[bucket][tile] (bucket-major).
__global__ void k_histT(const int* __restrict__ dst, int* __restrict__ hmat,
                        int E, int ntiles, int nbk){
  __shared__ int cnt[1024];
  int tile = blockIdx.x, lt = threadIdx.x;
  for (int b = lt; b < nbk; b += 256) cnt[b] = 0;
  __syncthreads();
  int tb = tile*TTILE;
  #pragma unroll 4
  for (int r = 0; r < TTILE/256; ++r){
    int e = tb + r*256 + lt;
    if (e < E) atomicAdd(&cnt[dst[e] >> BSH], 1);
  }
  __syncthreads();
  for (int b = lt; b < nbk; b += 256) hmat[(size_t)b*ntiles + tile] = cnt[b];
}

// Partition pass: streaming re-read of edge arrays; LDS ranks; write int4
// records {src,w,c,dst} to exact (bucket,tile) offsets -> bucket-grouped tmp.
__global__ void k_partition(const int* __restrict__ ei, const float* __restrict__ ew,
                            const float* __restrict__ ce, const int* __restrict__ gofs,
                            int4* __restrict__ tmp, int E, int ntiles, int nbk){
  __shared__ int cnt[1024];
  __shared__ int base[1024];
  int tile = blockIdx.x, lt = threadIdx.x;
  for (int b = lt; b < nbk; b += 256){
    cnt[b] = 0;
    base[b] = gofs[(size_t)b*ntiles + tile];
  }
  __syncthreads();
  int tb = tile*TTILE;
  #pragma unroll 4
  for (int r = 0; r < TTILE/256; ++r){
    int e = tb + r*256 + lt;
    if (e < E){
      int d = ei[E+e];
      int bk = d >> BSH;
      int rk = atomicAdd(&cnt[bk], 1);
      tmp[base[bk] + rk] = make_int4(ei[e], __float_as_int(ew[e]),
                                     __float_as_int(ce[e]), d);
    }
  }
}

// Per-bucket finalize: LDS dst-histogram -> scan -> rowstart + exact placement.
__global__ void k_bucket(const int4* __restrict__ tmp, const int* __restrict__ gofs,
                         int* __restrict__ rowstart, int4* __restrict__ csr,
                         int n, int E, int ntiles, int nbk){
  __shared__ int cnt[BKN];
  __shared__ int sc[BKN];
  __shared__ int cur[BKN];
  int b = blockIdx.x, lt = threadIdx.x;
  int d0 = b << BSH;
  int segs = gofs[(size_t)b*ntiles];
  int sege = (b+1 < nbk) ? gofs[(size_t)(b+1)*ntiles] : E;
  if (lt < BKN) cnt[lt] = 0;
  __syncthreads();
  for (int j = segs + lt; j < sege; j += 256)
    atomicAdd(&cnt[tmp[j].w & (BKN-1)], 1);
  __syncthreads();
  if (lt < BKN) sc[lt] = cnt[lt];
  __syncthreads();
  #pragma unroll
  for (int off = 1; off < BKN; off <<= 1){
    int u = (lt >= off && lt < BKN) ? sc[lt-off] : 0;
    __syncthreads();
    if (lt < BKN) sc[lt] += u;
    __syncthreads();
  }
  if (lt < BKN){
    int excl = segs + sc[lt] - cnt[lt];
    cur[lt] = excl;
    int d = d0 + lt;
    if (d < n) rowstart[d] = excl;
  }
  if (b == 0 && lt == 0) rowstart[n] = E;
  __syncthreads();
  for (int j = segs + lt; j < sege; j += 256){
    int4 rec = tmp[j];
    int pos = atomicAdd(&cur[rec.w & (BKN-1)], 1);
    csr[pos] = rec;
  }
}

// Fused init+pre layer1: h0 = relu(x@wi+bi) in regs; xl1/xr1 = h0@Wl/Wr + b.
__global__ void k_pre1(const float* __restrict__ x, const float* __restrict__ wi,
                       const float* __restrict__ bi, const float* __restrict__ wl,
                       const float* __restrict__ bl, const float* __restrict__ wr,
                       const float* __restrict__ br, float* __restrict__ xl,
                       float* __restrict__ xr, int n){
  int i = blockIdx.x*blockDim.x + threadIdx.x;
  if (i >= n) return;
  float xi[5];
  #pragma unroll
  for (int j = 0; j < 5; ++j) xi[j] = x[i*5+j];
  float h[8];
  #pragma unroll
  for (int o = 0; o < 8; ++o){
    float acc = bi[o];
    #pragma unroll
    for (int j = 0; j < 5; ++j) acc += xi[j]*wi[j*8+o];
    h[o] = fmaxf(acc, 0.f);
  }
  #pragma unroll
  for (int o = 0; o < 16; ++o){
    float a = bl[o], r = br[o];
    #pragma unroll
    for (int j = 0; j < 8; ++j){ a += h[j]*wl[j*16+o]; r += h[j]*wr[j*16+o]; }
    xl[(size_t)i*16+o] = a;
    xr[(size_t)i*16+o] = r;
  }
}

// xl = hin@Wl+bl, xr = hin@Wr+br (layer2: 16 -> 32).
__global__ void k_pre2(const float* __restrict__ hin,
                       const float* __restrict__ wl, const float* __restrict__ bl,
                       const float* __restrict__ wr, const float* __restrict__ br,
                       float* __restrict__ xl, float* __restrict__ xr, int n){
  int i = blockIdx.x*blockDim.x + threadIdx.x;
  if (i >= n) return;
  float h[16];
  #pragma unroll
  for (int j = 0; j < 16; ++j) h[j] = hin[(size_t)i*16+j];
  #pragma unroll
  for (int o = 0; o < 32; ++o){
    float a = bl[o], r = br[o];
    #pragma unroll
    for (int j = 0; j < 16; ++j){ a += h[j]*wl[j*32+o]; r += h[j]*wr[j*32+o]; }
    xl[(size_t)i*32+o] = a;
    xr[(size_t)i*32+o] = r;
  }
}

// Layer-1 aggregation, split-K: 8 threads/node = (head, edge-half).
__global__ void k_agg1(const int* __restrict__ rowstart, const int4* __restrict__ csr,
                       const float* __restrict__ xl, const float* __restrict__ xr,
                       const float* __restrict__ we, const float* __restrict__ att,
                       const float* __restrict__ bias, float* __restrict__ hout, int n){
  constexpr int C = 4, HC = 16;
  int t = blockIdx.x*blockDim.x + threadIdx.x;
  int i = t >> 3, l = t & 7, head = l & 3, half = l >> 2;
  if (i >= n) return;
  float weA[C], weB[C], AT[C], BS[C];
  #pragma unroll
  for (int c = 0; c < C; ++c){
    int o = head*C + c;
    weA[c] = we[o]; weB[c] = we[HC+o]; AT[c] = att[o]; BS[c] = bias[o];
  }
  float XR[C];
  {
    float4 b = *(const float4*)(xr + (size_t)i*HC + head*C);
    XR[0]=b.x; XR[1]=b.y; XR[2]=b.z; XR[3]=b.w;
  }
  float m = -3.0e38f, den = 0.f, sw = 0.f, sc = 0.f;
  float num[C] = {0.f,0.f,0.f,0.f};
  int rs = rowstart[i], re = rowstart[i+1];
  int mid = rs + ((re - rs) >> 1);
  int jb = half ? mid : rs, je = half ? re : mid;
  int j = jb;
  for (; j + 2 <= je; j += 2){
    int4 pa = csr[j], pb = csr[j+1];
    float4 qa = *(const float4*)(xl + (size_t)pa.x*HC + head*C);
    float4 qb = *(const float4*)(xl + (size_t)pb.x*HC + head*C);
    float f0a = __int_as_float(pa.y), f1a = __int_as_float(pa.z);
    float f0b = __int_as_float(pb.y), f1b = __int_as_float(pb.z);
    sw += f0a + f0b; sc += f1a + f1b;
    float XA[C] = {qa.x,qa.y,qa.z,qa.w};
    float XB[C] = {qb.x,qb.y,qb.z,qb.w};
    float aa = 0.f, ab = 0.f;
    #pragma unroll
    for (int c = 0; c < C; ++c) aa += AT[c]*lrelu(XA[c] + XR[c] + f0a*weA[c] + f1a*weB[c]);
    #pragma unroll
    for (int c = 0; c < C; ++c) ab += AT[c]*lrelu(XB[c] + XR[c] + f0b*weA[c] + f1b*weB[c]);
    float nm = fmaxf(m, aa);
    float r = __expf(m - nm), ex = __expf(aa - nm);
    den = den*r + ex;
    #pragma unroll
    for (int c = 0; c < C; ++c) num[c] = num[c]*r + ex*XA[c];
    m = nm;
    nm = fmaxf(m, ab); r = __expf(m - nm); ex = __expf(ab - nm);
    den = den*r + ex;
    #pragma unroll
    for (int c = 0; c < C; ++c) num[c] = num[c]*r + ex*XB[c];
    m = nm;
  }
  if (j < je){
    int4 pa = csr[j];
    float4 qa = *(const float4*)(xl + (size_t)pa.x*HC + head*C);
    float f0a = __int_as_float(pa.y), f1a = __int_as_float(pa.z);
    sw += f0a; sc += f1a;
    float XA[C] = {qa.x,qa.y,qa.z,qa.w};
    float aa = 0.f;
    #pragma unroll
    for (int c = 0; c < C; ++c) aa += AT[c]*lrelu(XA[c] + XR[c] + f0a*weA[c] + f1a*weB[c]);
    float nm = fmaxf(m, aa);
    float r = __expf(m - nm), ex = __expf(aa - nm);
    den = den*r + ex;
    #pragma unroll
    for (int c = 0; c < C; ++c) num[c] = num[c]*r + ex*XA[c];
    m = nm;
  }
  {
    float mo  = __shfl_xor(m, 4);
    float dno = __shfl_xor(den, 4);
    float swo = __shfl_xor(sw, 4), sco = __shfl_xor(sc, 4);
    float nm = fmaxf(m, mo);
    float r0 = __expf(m - nm), r1 = __expf(mo - nm);
    den = den*r0 + dno*r1;
    #pragma unroll
    for (int c = 0; c < C; ++c){
      float no = __shfl_xor(num[c], 4);
      num[c] = num[c]*r0 + no*r1;
    }
    m = nm; sw += swo; sc += sco;
  }
  float cf = fmaxf((float)(re - rs), 1.f);
  float la0 = sw/cf, la1 = sc/cf;
  float4 qs = *(const float4*)(xl + (size_t)i*HC + head*C);
  float XS[C] = {qs.x,qs.y,qs.z,qs.w};
  float as = 0.f;
  #pragma unroll
  for (int c = 0; c < C; ++c) as += AT[c]*lrelu(XS[c] + XR[c] + la0*weA[c] + la1*weB[c]);
  float nm = fmaxf(m, as);
  float r = __expf(m - nm), ex = __expf(as - nm);
  den = den*r + ex;
  #pragma unroll
  for (int c = 0; c < C; ++c) num[c] = num[c]*r + ex*XS[c];
  if (half == 0){
    float inv = 1.f/den;
    #pragma unroll
    for (int c = 0; c < C; ++c)
      hout[(size_t)i*HC + head*C + c] = fmaxf(num[c]*inv + BS[c], 0.f);
  }
}

// Layer-2 aggregation, split-K (8 thr/node) + fused fc/edge-MLP epilogue.
__global__ void k_agg2f(const int* __restrict__ rowstart, const int4* __restrict__ csr,
                        const float* __restrict__ xl, const float* __restrict__ xr,
                        const float* __restrict__ we, const float* __restrict__ att,
                        const float* __restrict__ bias, const float* __restrict__ wfc,
                        const float* __restrict__ bfc, const float* __restrict__ wc,
                        float* __restrict__ asrc, float* __restrict__ bdst, int n){
  constexpr int C = 8, HC = 32;
  __shared__ float s_h[32*33];
  __shared__ float s_w[1024];
  __shared__ float s_wc[134];
  int lt = threadIdx.x;
  for (int k = lt; k < 1024; k += 256) s_w[k] = wfc[k];
  if (lt < 134) s_wc[lt] = wc[lt];
  int t = blockIdx.x*blockDim.x + lt;
  int i = t >> 3, l = lt & 7, head = l & 3, half = l >> 2;
  bool valid = i < n;
  int ic = valid ? i : 0;
  float weA[C], weB[C], AT[C], BS[C];
  #pragma unroll
  for (int c = 0; c < C; ++c){
    int o = head*C + c;
    weA[c] = we[o]; weB[c] = we[HC+o]; AT[c] = att[o]; BS[c] = bias[o];
  }
  float XR[C];
  {
    const float4* pr = (const float4*)(xr + (size_t)ic*HC + head*C);
    float4 b0 = pr[0], b1 = pr[1];
    XR[0]=b0.x; XR[1]=b0.y; XR[2]=b0.z; XR[3]=b0.w;
    XR[4]=b1.x; XR[5]=b1.y; XR[6]=b1.z; XR[7]=b1.w;
  }
  float m = -3.0e38f, den = 0.f, sw = 0.f, sc = 0.f;
  float num[C] = {0.f,0.f,0.f,0.f,0.f,0.f,0.f,0.f};
  int rs = 0, re = 0;
  if (valid){ rs = rowstart[i]; re = rowstart[i+1]; }
  int mid = rs + ((re - rs) >> 1);
  int jb = half ? mid : rs, je = half ? re : mid;
  int j = jb;
  for (; j + 2 <= je; j += 2){
    int4 pa = csr[j], pb = csr[j+1];
    const float4* qa = (const float4*)(xl + (size_t)pa.x*HC + head*C);
    const float4* qb = (const float4*)(xl + (size_t)pb.x*HC + head*C);
    float4 a0 = qa[0], a1 = qa[1], b0 = qb[0], b1 = qb[1];
    float f0a = __int_as_float(pa.y), f1a = __int_as_float(pa.z);
    float f0b = __int_as_float(pb.y), f1b = __int_as_float(pb.z);
    sw += f0a + f0b; sc += f1a + f1b;
    float XA[C] = {a0.x,a0.y,a0.z,a0.w,a1.x,a1.y,a1.z,a1.w};
    float XB[C] = {b0.x,b0.y,b0.z,b0.w,b1.x,b1.y,b1.z,b1.w};
    float aa = 0.f, ab = 0.f;
    #pragma unroll
    for (int c = 0; c < C; ++c) aa += AT[c]*lrelu(XA[c] + XR[c] + f0a*weA[c] + f1a*weB[c]);
    #pragma unroll
    for (int c = 0; c < C; ++c) ab += AT[c]*lrelu(XB[c] + XR[c] + f0b*weA[c] + f1b*weB[c]);
    float nm = fmaxf(m, aa);
    float r = __expf(m - nm), ex = __expf(aa - nm);
    den = den*r + ex;
    #pragma unroll
    for (int c = 0; c < C; ++c) num[c] = num[c]*r + ex*XA[c];
    m = nm;
    nm = fmaxf(m, ab); r = __expf(m - nm); ex = __expf(ab - nm);
    den = den*r + ex;
    #pragma unroll
    for (int c = 0; c < C; ++c) num[c] = num[c]*r + ex*XB[c];
    m = nm;
  }
  if (j < je){
    int4 pa = csr[j];
    const float4* qa = (const float4*)(xl + (size_t)pa.x*HC + head*C);
    float4 a0 = qa[0], a1 = qa[1];
    float f0a = __int_as_float(pa.y), f1a = __int_as_float(pa.z);
    sw += f0a; sc += f1a;
    float XA[C] = {a0.x,a0.y,a0.z,a0.w,a1.x,a1.y,a1.z,a1.w};
    float aa = 0.f;
    #pragma unroll
    for (int c = 0; c < C; ++c) aa += AT[c]*lrelu(XA[c] + XR[c] + f0a*weA[c] + f1a*weB[c]);
    float nm = fmaxf(m, aa);
    float r = __expf(m - nm), ex = __expf(aa - nm);
    den = den*r + ex;
    #pragma unroll
    for (int c = 0; c < C; ++c) num[c] = num[c]*r + ex*XA[c];
    m = nm;
  }
  {
    float mo  = __shfl_xor(m, 4);
    float dno = __shfl_xor(den, 4);
    float swo = __shfl_xor(sw, 4), sco = __shfl_xor(sc, 4);
    float nm = fmaxf(m, mo);
    float r0 = __expf(m - nm), r1 = __expf(mo - nm);
    den = den*r0 + dno*r1;
    #pragma unroll
    for (int c = 0; c < C; ++c){
      float no = __shfl_xor(num[c], 4);
      num[c] = num[c]*r0 + no*r1;
    }
    m = nm; sw += swo; sc += sco;
  }
  if (valid){
    float cf = fmaxf((float)(re - rs), 1.f);
    float la0 = sw/cf, la1 = sc/cf;
    const float4* pl = (const float4*)(xl + (size_t)i*HC + head*C);
    float4 s0 = pl[0], s1 = pl[1];
    float XS[C] = {s0.x,s0.y,s0.z,s0.w,s1.x,s1.y,s1.z,s1.w};
    float as = 0.f;
    #pragma unroll
    for (int c = 0; c < C; ++c) as += AT[c]*lrelu(XS[c] + XR[c] + la0*weA[c] + la1*weB[c]);
    float nm = fmaxf(m, as);
    float r = __expf(m - nm), ex = __expf(as - nm);
    den = den*r + ex;
    #pragma unroll
    for (int c = 0; c < C; ++c) num[c] = num[c]*r + ex*XS[c];
  }
  int ln = lt >> 3;
  if (half == 0){
    float inv = valid ? 1.f/den : 0.f;
    #pragma unroll
    for (int c = 0; c < C; ++c)
      s_h[ln*33 + head*C + c] = valid ? fmaxf(num[c]*inv + BS[c], 0.f) : 0.f;
  }
  __syncthreads();
  float hl[32];
  #pragma unroll
  for (int j2 = 0; j2 < 32; ++j2) hl[j2] = s_h[ln*33 + j2];
  float pa0=0.f, pa1=0.f, pb0=0.f, pb1=0.f;
  #pragma unroll
  for (int k = 0; k < 4; ++k){
    int o = l*4 + k;
    float acc = bfc[o];
    #pragma unroll
    for (int j2 = 0; j2 < 32; ++j2) acc += hl[j2]*s_w[j2*32+o];
    float f = fmaxf(acc, 0.f);
    pa0 += f*s_wc[(2+o)*2];  pa1 += f*s_wc[(2+o)*2+1];
    pb0 += f*s_wc[(34+o)*2]; pb1 += f*s_wc[(34+o)*2+1];
  }
  pa0 += __shfl_xor(pa0,1); pa0 += __shfl_xor(pa0,2); pa0 += __shfl_xor(pa0,4);
  pa1 += __shfl_xor(pa1,1); pa1 += __shfl_xor(pa1,2); pa1 += __shfl_xor(pa1,4);
  pb0 += __shfl_xor(pb0,1); pb0 += __shfl_xor(pb0,2); pb0 += __shfl_xor(pb0,4);
  pb1 += __shfl_xor(pb1,1); pb1 += __shfl_xor(pb1,2); pb1 += __shfl_xor(pb1,4);
  if (valid){
    if (l == 0)      ((float2*)asrc)[i] = make_float2(pa0, pa1);
    else if (l == 1) ((float2*)bdst)[i] = make_float2(pb0, pb1);
  }
}

// out[e] = ef[e]@Wc[0:2] + asrc[src] + bdst[dst] + bc  (float2 store)
__global__ void k_edge_final(const int* __restrict__ ei, const float* __restrict__ ew,
                             const float* __restrict__ ce, const float* __restrict__ asrc,
                             const float* __restrict__ bdst, const float* __restrict__ wc,
                             const float* __restrict__ bc, float2* __restrict__ out, int E){
  int e = blockIdx.x*blockDim.x + threadIdx.x;
  if (e >= E) return;
  int s = ei[e], d = ei[E+e];
  float f0 = ew[e], f1 = ce[e];
  float2 a = ((const float2*)asrc)[s];
  float2 b = ((const float2*)bdst)[d];
  out[e] = make_float2(f0*wc[0] + f1*wc[2] + a.x + b.x + bc[0],
                       f0*wc[1] + f1*wc[3] + a.y + b.y + bc[1]);
}

extern "C" void kernel_launch(void* const* d_in, const int* in_sizes, int n_in,
                              void* d_out, int out_size, void* d_ws, size_t ws_size,
                              hipStream_t stream){
  const float* x     = (const float*)d_in[0];
  const int*   ei    = (const int*)  d_in[1];
  const float* ew    = (const float*)d_in[2];
  const float* ce    = (const float*)d_in[3];
  const float* w_init= (const float*)d_in[4];
  const float* b_init= (const float*)d_in[5];
  const float* w1l   = (const float*)d_in[6];
  const float* b1l   = (const float*)d_in[7];
  const float* w1r   = (const float*)d_in[8];
  const float* b1r   = (const float*)d_in[9];
  const float* w1e   = (const float*)d_in[10];
  const float* att1  = (const float*)d_in[11];
  const float* bias1 = (const float*)d_in[12];
  const float* w2l   = (const float*)d_in[13];
  const float* b2l   = (const float*)d_in[14];
  const float* w2r   = (const float*)d_in[15];
  const float* b2r   = (const float*)d_in[16];
  const float* w2e   = (const float*)d_in[17];
  const float* att2  = (const float*)d_in[18];
  const float* bias2 = (const float*)d_in[19];
  const float* w_fc  = (const float*)d_in[20];
  const float* b_fc  = (const float*)d_in[21];
  const float* w_e1  = (const float*)d_in[22];
  const float* b_e1  = (const float*)d_in[23];
  const float* w_e2  = (const float*)d_in[24];
  const float* b_e2  = (const float*)d_in[25];

  const int n = in_sizes[0]/5;     // 100000
  const int E = in_sizes[2];       // 3200000
  const int ntiles = (E + TTILE - 1) / TTILE;     // ~782
  const int nbk    = (n + BKN - 1) >> BSH;        // ~782 buckets
  const int M      = nbk * ntiles;                // ~611K
  const int nbA    = (M + 255) >> 8;              // ~2389 (>1024 -> 3-level)
  const int nbB    = (nbA + 255) >> 8;            // ~10

  // ---- workspace layout: 128B-aligned (32 x 4B units) ----
  int*   W32 = (int*)d_ws;
  float* Wf  = (float*)d_ws;
  size_t off = 0;
  auto nxt = [&off](size_t cnt){ size_t p = off; off += (cnt + 31) & ~(size_t)31; return p; };
  int*   rowstart = W32 + nxt((size_t)n + 1);
  int*   bsum     = W32 + nxt(nbA);
  int*   boffs    = W32 + nxt(nbA);
  int*   bsum2    = W32 + nxt(nbB);
  int*   boffs2   = W32 + nxt(nbB);
  int*   hmat     = W32 + nxt(M);
  int*   gofs     = W32 + nxt(M);
  float* wc       = Wf  + nxt(160);
  float* bc       = wc + 132;
  int4*  csr      = (int4*)(W32 + nxt((size_t)4*E));
  size_t na = ((size_t)n + 31) & ~(size_t)31;
  size_t bigsz = (size_t)4*E > 80*na ? (size_t)4*E : 80*na;
  float* S    = Wf + nxt(bigsz);
  int4*  tmp  = (int4*)S;
  float* xl1  = S;              // 16n, dead after agg1
  float* xr1  = S + 16*na;      // 16n, dead after agg1
  float* h1   = S + 32*na;      // 16n, dead after pre2
  float* xl2  = S;              // 32n (over xl1/xr1)
  float* xr2  = S + 48*na;      // 32n
  float* asrc = S + 32*na;      // 2n  (over h1, dead)
  float* bdst = S + 34*na;      // 2n

  dim3 blk(256);
  dim3 ge((E + 255)/256), gn((n + 255)/256), gn8(((size_t)8*n + 255)/256);

  k_wcomb<<<1,192,0,stream>>>(w_e1,b_e1,w_e2,b_e2,wc,bc);

  // ---- CSR build: LDS counting sort + 3-level hierarchical scan ----
  k_histT<<<ntiles,256,0,stream>>>(ei + E, hmat, E, ntiles, nbk);
  k_scan1<<<nbA,256,0,stream>>>(hmat,bsum,M);
  k_scan1<<<nbB,256,0,stream>>>(bsum,bsum2,nbA);
  k_scan2<<<1,1024,0,stream>>>(bsum2,boffs2,nbB);
  k_scan3g<<<nbB,256,0,stream>>>(bsum,boffs2,boffs,nbA);
  k_scan3g<<<nbA,256,0,stream>>>(hmat,boffs,gofs,M);
  k_partition<<<ntiles,256,0,stream>>>(ei,ew,ce,gofs,tmp,E,ntiles,nbk);
  k_bucket<<<nbk,256,0,stream>>>(tmp,gofs,rowstart,csr,n,E,ntiles,nbk);

  // ---- GATv2 layer 1 (in 8, C=4) ----
  k_pre1<<<gn,blk,0,stream>>>(x,w_init,b_init,w1l,b1l,w1r,b1r,xl1,xr1,n);
  k_agg1<<<gn8,blk,0,stream>>>(rowstart,csr,xl1,xr1,w1e,att1,bias1,h1,n);

  // ---- GATv2 layer 2 (in 16, C=8) + fused fc/edge-MLP node terms ----
  k_pre2<<<gn,blk,0,stream>>>(h1,w2l,b2l,w2r,b2r,xl2,xr2,n);
  k_agg2f<<<gn8,blk,0,stream>>>(rowstart,csr,xl2,xr2,w2e,att2,bias2,w_fc,b_fc,wc,asrc,bdst,n);

  // ---- edge scores ----
  k_edge_final<<<ge,blk,0,stream>>>(ei,ew,ce,asrc,bdst,wc,bc,(float2*)d_out,E);
}